// Round 8
// baseline (652.546 us; speedup 1.0000x reference)
//
#include <hip/hip_runtime.h>
#include <stdint.h>

// Problem constants
#define N_TOK 32768   // B*H*W tokens
#define DIM   256
#define KCB   8192
#define HWSZ  1024

// ---- workspace layout (float offsets) ---- total 8,011,776 floats = 32.0 MB
#define WS_FLATB   0u          // bf16 flat [32768][256]  (4,194,304)
#define WS_CBT     4194304u    // bf16 cb TILED [512 cg][32 dg][16 codes][8 dims] (1,048,576 floats)
#define WS_A32     5242880u    // np-fp32 ||z||^2         32,768
#define WS_B32     5275648u    // np-fp32 ||e||^2         8,192
#define WS_IDX     5283840u    // argmin (int)            32,768
#define WS_CAND    5316608u    // [token][16] int         524,288
#define WS_ICNT    5840896u    // int histogram           8,192   <- memset from here
#define WS_CUR     5849088u    // int cursors             8,192   <- memset through here
#define WS_OFFS    5857280u    // int exclusive offsets   8,192
#define WS_PERM    5865472u    // int token permutation   32,768
#define WS_LPART   5898240u    // per-block loss partials 2,048 doubles (4,096 floats)
#define WS_TOTAL   8011776u
#define WS_MEMSET_LEN 16384u   // ICNT + CUR only

// ---- output layout (float offsets) ----
#define O_LOSS 0u
#define O_Q    1u
#define O_IDX  8388609u
#define O_CNT  8421377u
#define O_W    8429569u
#define O_CB   10526721u

typedef __attribute__((ext_vector_type(8))) short bf16x8;
typedef __attribute__((ext_vector_type(4))) float f32x4;

__device__ __forceinline__ void g2lds16(const void* gp, void* lp){
  __builtin_amdgcn_global_load_lds(
      (const __attribute__((address_space(1))) void*)gp,
      (__attribute__((address_space(3))) void*)lp, 16, 0, 0);
}

__device__ __forceinline__ unsigned short f2b(float f){   // fp32 -> bf16 RNE
  unsigned u = __float_as_uint(f);
  return (unsigned short)((u + 0x7FFFu + ((u >> 16) & 1u)) >> 16);
}

__device__ __forceinline__ unsigned umin2(unsigned a, unsigned b){ return a < b ? a : b; }
__device__ __forceinline__ unsigned umax2(unsigned a, unsigned b){ return a > b ? a : b; }

// ============ prep: squared norms, numpy pairwise fp32 order ============
__device__ __forceinline__ float np_pairwise_sq(const float* __restrict__ p, int stride){
  #pragma clang fp contract(off)
  float h[2];
  #pragma unroll
  for (int half = 0; half < 2; half++){
    const float* q = p + half * 128 * stride;
    float r[8];
    #pragma unroll
    for (int j = 0; j < 8; j++){ float z = q[j * stride]; r[j] = z * z; }
    for (int i = 8; i < 128; i += 8){
      #pragma unroll
      for (int j = 0; j < 8; j++){ float z = q[(i + j) * stride]; r[j] = r[j] + z * z; }
    }
    h[half] = ((r[0] + r[1]) + (r[2] + r[3])) + ((r[4] + r[5]) + (r[6] + r[7]));
  }
  return h[0] + h[1];
}

// ============ fused prep: {transpose + a32 single-pass} | cb->bf16 tiled | b32 ============
// blocks [0,2048): x [B,C,H,W] -> flatB bf16 [token][c] AND a32 (x read ONCE).
// blocks [2048,4096): codebook fp32 -> bf16, FRAGMENT-MAJOR tiled layout:
//   cbT[(k>>4)*32 + (d>>3)][ (k&15)*8 + (d&7) ]  (128-short inner blocks)
//   so a k_dist wave's B-fragment load is contiguous 1KB (lane*16B).
// blocks [4096,4128): b32 norms
__global__ void k_prep(const float* __restrict__ x, const float* __restrict__ cb,
                       unsigned short* __restrict__ flatB, unsigned short* __restrict__ cbT,
                       float* __restrict__ a32, float* __restrict__ b32)
{
  const int bx = blockIdx.x;
  const int t = threadIdx.x;
  if (bx < 2048){
    __shared__ float tile[256][17];
    const int b = bx >> 6, ht = bx & 63;
    const int hw0 = ht * 16;
    const int n0 = b * 1024 + hw0;
    const int wv = t >> 6, lane = t & 63;
    {
      const int cr = lane >> 2, hq = (lane & 3) * 4;
      #pragma unroll
      for (int j = 0; j < 4; j++){
        const int c = wv * 64 + j * 16 + cr;
        float4 v = *(const float4*)(x + ((size_t)(b * 256 + c) << 10) + hw0 + hq);
        tile[c][hq] = v.x; tile[c][hq+1] = v.y; tile[c][hq+2] = v.z; tile[c][hq+3] = v.w;
      }
    }
    __syncthreads();
    #pragma unroll
    for (int j = 0; j < 4; j++){
      const int tok = wv * 4 + j;
      ushort4 o = { f2b(tile[lane*4+0][tok]), f2b(tile[lane*4+1][tok]),
                    f2b(tile[lane*4+2][tok]), f2b(tile[lane*4+3][tok]) };
      *(ushort4*)(flatB + ((size_t)(n0 + tok) << 8) + lane * 4) = o;
    }
    if (t < 16){
      #pragma clang fp contract(off)
      float h[2];
      #pragma unroll
      for (int half = 0; half < 2; half++){
        float r[8];
        #pragma unroll
        for (int j = 0; j < 8; j++){ float z = tile[half*128 + j][t]; r[j] = z * z; }
        for (int i = 8; i < 128; i += 8){
          #pragma unroll
          for (int j = 0; j < 8; j++){ float z = tile[half*128 + i + j][t]; r[j] = r[j] + z * z; }
        }
        h[half] = ((r[0] + r[1]) + (r[2] + r[3])) + ((r[4] + r[5]) + (r[6] + r[7]));
      }
      a32[n0 + t] = h[0] + h[1];
    }
  } else if (bx < 4096){
    const int g = (bx - 2048) * 256 + t;    // 524,288 element-quads
    const int k = g >> 6;                   // code
    const int d0 = (g & 63) * 4;            // dim (multiple of 4)
    float4 v = *(const float4*)(cb + (size_t)g * 4);
    ushort4 o = { f2b(v.x), f2b(v.y), f2b(v.z), f2b(v.w) };
    const size_t toff = ((size_t)((k >> 4) * 32 + (d0 >> 3))) * 128 + (k & 15) * 8 + (d0 & 7);
    *(ushort4*)(cbT + toff) = o;
  } else {
    const int g = (bx - 4096) * 256 + t;    // 8,192
    if (g < KCB) b32[g] = np_pairwise_sq(cb + (size_t)g * 256, 1);
  }
}

// ============ phase 1: bf16-MFMA distance GEMM + top-8 candidates/half ============
// BARRIER-FREE main loop: B fragments read DIRECTLY from L2-resident cbT
// (fragment-major layout -> each load is contiguous 1KB across the wave).
// A: k0..127 staged once into 32KB LDS (proven g2lds+swizzle); k128..255 in
// 64 VGPR via one-time direct global loads. No shared mutable state in the
// chunk loop -> zero __syncthreads until the final merge. 3 blocks/CU.
__launch_bounds__(256, 3)
__global__ void k_dist(const unsigned short* __restrict__ flatB,
                       const unsigned short* __restrict__ cbT,
                       const float* __restrict__ b32,
                       int* __restrict__ cand)
{
  __shared__ __align__(16) unsigned short A1[128 * 128];   // 32 KB: [row][k0..127]

  const int tid = threadIdx.x;
  const int bx = blockIdx.x;             // 512 = 256 token-tiles x 2 halves
  const int tt = bx >> 1, h = bx & 1;
  const int tok0 = tt * 128;
  const int wv = tid >> 6, lane = tid & 63;
  const int wy = wv >> 1, wx = wv & 1;
  const int l4 = lane >> 4, lm = lane & 15;

  const unsigned short* fB = flatB + (size_t)tok0 * 256;

  // ---- stage A1 (k 0..127) into LDS ----
  {
    const int r = lane >> 4, p = lane & 15;
    #pragma unroll
    for (int j = 0; j < 8; j++){
      const int row = wv * 32 + j * 4 + r;
      const int gc = p ^ (row & 15);
      g2lds16((const char*)fB + (size_t)row * 512 + (gc << 4),
              (char*)A1 + (wv * 32 + j * 4) * 256);
    }
  }

  // ---- A k128..255 fragments: one-time direct global loads (64 VGPR) ----
  bf16x8 a2[4][4];
  #pragma unroll
  for (int ks4 = 0; ks4 < 4; ks4++)
    #pragma unroll
    for (int ii = 0; ii < 4; ii++){
      const int m = wy * 64 + ii * 16 + lm;
      const int dg = 16 + ks4 * 4 + l4;          // dim8-group
      a2[ks4][ii] = *(const bf16x8*)((const char*)fB + (size_t)m * 512 + dg * 16);
    }
  __syncthreads();   // A1 landed (barrier drains the g2lds queue)

  // ---- loop-invariant offsets ----
  unsigned aoff[4][4];   // [kg 0..3][ii] byte offsets into A1
  #pragma unroll
  for (int kg = 0; kg < 4; kg++)
    #pragma unroll
    for (int ii = 0; ii < 4; ii++){
      const int m = wy * 64 + ii * 16 + lm;
      const int ca = kg * 4 + l4;
      aoff[kg][ii] = (unsigned)(m * 256 + ((ca ^ (m & 15)) << 4));
    }
  // B base pointers: cg block = 8KB; fragment addr = base + cc*64KB + kg*1KB
  const char* bj[4];
  #pragma unroll
  for (int jj = 0; jj < 4; jj++){
    const int cg0 = h * 256 + wx * 4 + jj;       // 16-code group index
    bj[jj] = (const char*)cbT + (size_t)cg0 * 8192 + lane * 16;
  }

  unsigned k1[16], k2[16];
  #pragma unroll
  for (int i = 0; i < 16; i++){ k1[i] = 0xFFFFFFFFu; k2[i] = 0xFFFFFFFFu; }

  f32x4 acc[4][4];
  float bn125[4];

  for (int c = 0; c < 32; c++){
    const size_t cboff = (size_t)c << 16;        // c * 64KB (8 cg per chunk)
    #pragma unroll
    for (int jj = 0; jj < 4; jj++)
      bn125[jj] = b32[h * 4096 + c * 128 + wx * 64 + jj * 16 + lm] + 0.125f;
    #pragma unroll
    for (int ii = 0; ii < 4; ii++)
      #pragma unroll
      for (int jj = 0; jj < 4; jj++)
        acc[ii][jj] = (f32x4){0.f, 0.f, 0.f, 0.f};

    #pragma unroll
    for (int s = 0; s < 4; s++){
      #pragma unroll
      for (int ks2 = 0; ks2 < 2; ks2++){
        const int kg = s * 2 + ks2;              // 0..7 (compile-time)
        bf16x8 bf[4], af[4];
        #pragma unroll
        for (int jj = 0; jj < 4; jj++)
          bf[jj] = *(const bf16x8*)(bj[jj] + cboff + (unsigned)(kg << 10));
        if (kg < 4){
          #pragma unroll
          for (int ii = 0; ii < 4; ii++)
            af[ii] = *(const bf16x8*)((const char*)A1 + aoff[kg][ii]);
        } else {
          #pragma unroll
          for (int ii = 0; ii < 4; ii++) af[ii] = a2[kg - 4][ii];
        }
        #pragma unroll
        for (int ii = 0; ii < 4; ii++)
          #pragma unroll
          for (int jj = 0; jj < 4; jj++)
            acc[ii][jj] = __builtin_amdgcn_mfma_f32_16x16x32_bf16(af[ii], bf[jj], acc[ii][jj], 0, 0, 0);
      }
      if (s == 3){
        // rank by float bits of (b - 2s + 0.125) > 0; (c<<2)|jj in low 7 bits
        unsigned pk[4];
        #pragma unroll
        for (int jj = 0; jj < 4; jj++) pk[jj] = (unsigned)((c << 2) | jj);
        #pragma unroll
        for (int ii = 0; ii < 4; ii++){
          #pragma unroll
          for (int r = 0; r < 4; r++){
            const int rk = ii * 4 + r;
            unsigned kb[4];
            #pragma unroll
            for (int jj = 0; jj < 4; jj++){
              const float v = fmaf(-2.f, acc[ii][jj][r], bn125[jj]);
              kb[jj] = (__float_as_uint(v) & 0xFFFFFF80u) | pk[jj];
            }
            // smallest-2-of-4
            const unsigned lo01 = umin2(kb[0], kb[1]), hi01 = umax2(kb[0], kb[1]);
            const unsigned lo23 = umin2(kb[2], kb[3]), hi23 = umax2(kb[2], kb[3]);
            const unsigned s1 = umin2(lo01, lo23);
            const unsigned s2 = umin2(umax2(lo01, lo23), umin2(hi01, hi23));
            // merge two sorted pairs (k1,k2) x (s1,s2) -> top-2
            const unsigned t = umax2(k1[rk], s1);
            k1[rk] = umin2(k1[rk], s1);
            k2[rk] = umin2(umin2(k2[rk], t), s2);
          }
        }
      }
    }
  }

  // ---- finalize keys to (qi<<12)|col and merge: per row, top-8 of 64 keys ----
  __syncthreads();   // everyone done reading A1; reuse it as merge scratch
  const unsigned colbase = (unsigned)(wx * 64 + lm);
  auto fin = [colbase](unsigned key)->unsigned {
    const float v125 = __uint_as_float(key & 0xFFFFFF80u);
    int qi = (int)(v125 * 4194304.f);          // (v + 0.125) * 2^22
    qi = qi < 0 ? 0 : (qi > 0xFFFFF ? 0xFFFFF : qi);
    const unsigned cc = (key >> 2) & 31u, jj = key & 3u;
    return ((unsigned)qi << 12) | (cc * 128u + jj * 16u + colbase);
  };
  unsigned* red = (unsigned*)&A1[0];        // 32 KB = 8192 u32 = [128 rows][64]
  #pragma unroll
  for (int rk = 0; rk < 16; rk++){
    const int srow = wy * 64 + (rk >> 2) * 16 + l4 * 4 + (rk & 3);
    red[srow * 64 + wx * 32 + lm * 2 + 0] = fin(k1[rk]);
    red[srow * 64 + wx * 32 + lm * 2 + 1] = fin(k2[rk]);
  }
  __syncthreads();
  if (tid < 128){
    unsigned best[8];
    #pragma unroll
    for (int j = 0; j < 8; j++) best[j] = 0xFFFFFFFFu;
    for (int i = 0; i < 64; i++){
      unsigned k = red[tid * 64 + i];
      if (k < best[7]){
        best[7] = k;
        #pragma unroll
        for (int j = 7; j > 0; j--){
          if (best[j] < best[j-1]){ unsigned tmp = best[j]; best[j] = best[j-1]; best[j-1] = tmp; }
        }
      }
    }
    const size_t base = ((size_t)(tok0 + tid) * 2 + h) * 8;
    #pragma unroll
    for (int j = 0; j < 8; j++) cand[base + j] = h * 4096 + (int)(best[j] & 0xFFFu);
  }
}

// ========== phase 2: rescore + fused quantize/loss (16 lanes / token) ==========
__global__ void k_pick(const float* __restrict__ x, const float* __restrict__ cb,
                       const float* __restrict__ a32, const float* __restrict__ b32,
                       const int* __restrict__ cand, int* __restrict__ idx,
                       int* __restrict__ icnt, float* __restrict__ out_idx,
                       float* __restrict__ outq, double* __restrict__ lpart)
{
  __shared__ double wred[4];
  const int gt = blockIdx.x * 256 + threadIdx.x;
  const int wid = gt >> 6;                 // 0..8191
  const int lane = gt & 63;
  const int tq = lane & 3, cg = lane >> 2;
  const int n = wid * 4 + tq;              // token
  const int b = n >> 10, hw = n & 1023;

  const size_t xbase = (((size_t)(b * 256 + cg * 16)) << 10) + hw;
  float z[16];
  #pragma unroll
  for (int j = 0; j < 16; j++) z[j] = x[xbase + ((size_t)j << 10)];

  const float an = a32[n];
  float bestd = 3.4e38f; int besti = 0x7fffffff;
  for (int j = 0; j < 16; j++){
    const int ci = cand[(size_t)n * 16 + j];     // uniform across the 16 lanes
    if (ci < 0 || ci >= KCB) continue;
    const float* ep = cb + (size_t)ci * DIM + cg * 16;
    float4 e0 = *(const float4*)(ep + 0);
    float4 e1 = *(const float4*)(ep + 4);
    float4 e2 = *(const float4*)(ep + 8);
    float4 e3 = *(const float4*)(ep + 12);
    double se = (double)z[0]*e0.x + (double)z[1]*e0.y + (double)z[2]*e0.z + (double)z[3]*e0.w
              + (double)z[4]*e1.x + (double)z[5]*e1.y + (double)z[6]*e1.z + (double)z[7]*e1.w
              + (double)z[8]*e2.x + (double)z[9]*e2.y + (double)z[10]*e2.z + (double)z[11]*e2.w
              + (double)z[12]*e3.x + (double)z[13]*e3.y + (double)z[14]*e3.z + (double)z[15]*e3.w;
    se += __shfl_xor(se, 4, 64);
    se += __shfl_xor(se, 8, 64);
    se += __shfl_xor(se, 16, 64);
    se += __shfl_xor(se, 32, 64);
    const float A = an + b32[ci];
    const float d32 = (float)((double)A - 2.0 * se);
    if (d32 < bestd || (d32 == bestd && ci < besti)){ bestd = d32; besti = ci; }
  }

  // ---- fused quantize + loss ----
  double p = 0.0;
  {
    const float* ep = cb + (size_t)besti * DIM + cg * 16;
    float4 e0 = *(const float4*)(ep + 0);
    float4 e1 = *(const float4*)(ep + 4);
    float4 e2 = *(const float4*)(ep + 8);
    float4 e3 = *(const float4*)(ep + 12);
    float q[16] = { e0.x, e0.y, e0.z, e0.w, e1.x, e1.y, e1.z, e1.w,
                    e2.x, e2.y, e2.z, e2.w, e3.x, e3.y, e3.z, e3.w };
    #pragma unroll
    for (int j = 0; j < 16; j++){
      const float qd = q[j] - z[j];
      outq[xbase + ((size_t)j << 10)] = z[j] + qd;
      p += (double)(qd * qd);
    }
  }
  #pragma unroll
  for (int o = 32; o > 0; o >>= 1) p += __shfl_down(p, o, 64);
  if ((threadIdx.x & 63) == 0) wred[threadIdx.x >> 6] = p;

  if (cg == 0){
    idx[n] = besti;
    atomicAdd(icnt + besti, 1);
    out_idx[n] = (float)besti;
  }
  __syncthreads();
  if (threadIdx.x == 0) lpart[blockIdx.x] = (wred[0] + wred[1]) + (wred[2] + wred[3]);
}

// ========== bucket tokens by code (scan fused: each block scans icnt in LDS) ==========
__global__ void k_perm(const int* __restrict__ idx, const int* __restrict__ icnt,
                       int* __restrict__ cur, int* __restrict__ perm,
                       int* __restrict__ offs)
{
  __shared__ int offs_l[8192];
  __shared__ int sums[256];
  const int tid = threadIdx.x;
  int loc[32];
  int s = 0;
  #pragma unroll
  for (int i = 0; i < 32; i++){ loc[i] = s; s += icnt[tid * 32 + i]; }
  sums[tid] = s;
  #pragma unroll
  for (int off = 1; off < 256; off <<= 1){
    __syncthreads();
    const int add = (tid >= off) ? sums[tid - off] : 0;
    __syncthreads();
    sums[tid] += add;
  }
  __syncthreads();
  const int pre = (tid == 0) ? 0 : sums[tid - 1];
  #pragma unroll
  for (int i = 0; i < 32; i++) offs_l[tid * 32 + i] = pre + loc[i];
  if (blockIdx.x == 0){
    #pragma unroll
    for (int i = 0; i < 32; i++) offs[tid * 32 + i] = pre + loc[i];
  }
  __syncthreads();
  const int t = blockIdx.x * 256 + tid;        // 32,768
  const int code = idx[t];
  const int slot = atomicAdd(cur + code, 1);
  perm[offs_l[code] + slot] = t;
}

// ====== dw segment-sum + new_weight/new_codebook/new_count + e_loss (fused) ======
__global__ void k_dwf(const unsigned short* __restrict__ flatB,
                      const int* __restrict__ offs, const int* __restrict__ icnt,
                      const int* __restrict__ perm,
                      const float* __restrict__ ema_w, const float* __restrict__ ema_count,
                      const double* __restrict__ lpart, float* __restrict__ out)
{
  const int k = blockIdx.x;                   // 8192
  const int c = threadIdx.x;                  // 256
  const int start = offs[k], cnt = icnt[k];
  float s = 0.f;
  for (int i = 0; i < cnt; i++){
    const int n = perm[start + i];
    s += __uint_as_float(((unsigned)flatB[((size_t)n << 8) + c]) << 16);
  }
  // new_count (same exprs as before)
  float ct1 = ema_count[k] * 0.95f;
  float ct2 = 0.05f * (float)cnt;
  float sc  = ct1 + ct2;
  float sc2 = sc + 1e-5f;
  const float DEN = (float)(32768.0 + 8192.0 * 1e-5);
  float nc = (sc2 / DEN) * 32768.0f;
  if (c == 0) out[O_CNT + k] = nc;
  {
    #pragma clang fp contract(off)
    const int t = k * 256 + c;
    float w = ema_w[t];
    float t1 = w * 0.95f;
    float t2 = 0.05f * s;
    float nw = t1 + t2;        // np op order; bit-exact for empty codes (s==0)
    out[O_W + t]  = nw;
    out[O_CB + t] = nw / nc;
  }
  if (k == 0){
    __shared__ double sred[256];
    double ls = 0.0;
    for (int i = c; i < 2048; i += 256) ls += lpart[i];
    sred[c] = ls;
    __syncthreads();
    for (int off = 128; off > 0; off >>= 1){
      if (c < off) sred[c] += sred[c + off];
      __syncthreads();
    }
    if (c == 0) out[O_LOSS] = 0.25f * (float)(sred[0] / 8388608.0);
  }
}

// ===================== launch =====================
extern "C" void kernel_launch(void* const* d_in, const int* in_sizes, int n_in,
                              void* d_out, int out_size, void* d_ws, size_t ws_size,
                              hipStream_t stream)
{
  const float* x         = (const float*)d_in[0];
  const float* cb        = (const float*)d_in[1];
  const float* ema_count = (const float*)d_in[2];
  const float* ema_w     = (const float*)d_in[3];
  float* out = (float*)d_out;
  float* ws  = (float*)d_ws;

  unsigned short* flatB = (unsigned short*)(ws + WS_FLATB);
  unsigned short* cbT   = (unsigned short*)(ws + WS_CBT);
  float*  a32    = ws + WS_A32;
  float*  b32    = ws + WS_B32;
  int*    idxp   = (int*)(ws + WS_IDX);
  int*    candp  = (int*)(ws + WS_CAND);
  int*    icnt   = (int*)(ws + WS_ICNT);
  int*    curp   = (int*)(ws + WS_CUR);
  int*    offs   = (int*)(ws + WS_OFFS);
  int*    permp  = (int*)(ws + WS_PERM);
  double* lpart  = (double*)(ws + WS_LPART);

  (void)hipMemsetAsync(ws + WS_ICNT, 0, (size_t)WS_MEMSET_LEN * sizeof(float), stream);

  k_prep <<<4128, 256, 0, stream>>>(x, cb, flatB, cbT, a32, b32);
  k_dist <<<512,  256, 0, stream>>>(flatB, cbT, b32, candp);
  k_pick <<<2048, 256, 0, stream>>>(x, cb, a32, b32, candp, idxp, icnt,
                                    out + O_IDX, out + O_Q, lpart);
  k_perm <<<128,  256, 0, stream>>>(idxp, icnt, curp, permp, offs);
  k_dwf  <<<8192, 256, 0, stream>>>(flatB, offs, icnt, permp, ema_w, ema_count,
                                    lpart, out);
}

// Round 9
// 383.025 us; speedup vs baseline: 1.7037x; 1.7037x over previous
//
#include <hip/hip_runtime.h>
#include <stdint.h>

// Problem constants
#define N_TOK 32768   // B*H*W tokens
#define DIM   256
#define KCB   8192
#define HWSZ  1024

// ---- workspace layout (float offsets) ---- total 8,011,776 floats = 32.0 MB
#define WS_FLATB   0u          // bf16 flat [32768][256]  (4,194,304)
#define WS_CBB     4194304u    // bf16 cb [8192][256]     (1,048,576)
#define WS_A32     5242880u    // np-fp32 ||z||^2         32,768
#define WS_B32     5275648u    // np-fp32 ||e||^2         8,192
#define WS_IDX     5283840u    // argmin (int)            32,768
#define WS_CAND    5316608u    // [token][16] int         524,288
#define WS_ICNT    5840896u    // int histogram           8,192   <- memset from here
#define WS_CUR     5849088u    // int cursors             8,192   <- memset through here
#define WS_OFFS    5857280u    // int exclusive offsets   8,192
#define WS_PERM    5865472u    // int token permutation   32,768
#define WS_LPART   5898240u    // per-block loss partials 2,048 doubles (4,096 floats)
#define WS_TOTAL   8011776u
#define WS_MEMSET_LEN 16384u   // ICNT + CUR only

// ---- output layout (float offsets) ----
#define O_LOSS 0u
#define O_Q    1u
#define O_IDX  8388609u
#define O_CNT  8421377u
#define O_W    8429569u
#define O_CB   10526721u

typedef __attribute__((ext_vector_type(8))) short bf16x8;
typedef __attribute__((ext_vector_type(4))) float f32x4;

__device__ __forceinline__ void g2lds16(const void* gp, void* lp){
  __builtin_amdgcn_global_load_lds(
      (const __attribute__((address_space(1))) void*)gp,
      (__attribute__((address_space(3))) void*)lp, 16, 0, 0);
}

__device__ __forceinline__ unsigned short f2b(float f){   // fp32 -> bf16 RNE
  unsigned u = __float_as_uint(f);
  return (unsigned short)((u + 0x7FFFu + ((u >> 16) & 1u)) >> 16);
}

__device__ __forceinline__ unsigned umin2(unsigned a, unsigned b){ return a < b ? a : b; }
__device__ __forceinline__ unsigned umax2(unsigned a, unsigned b){ return a > b ? a : b; }

// ============ prep: squared norms, numpy pairwise fp32 order ============
__device__ __forceinline__ float np_pairwise_sq(const float* __restrict__ p, int stride){
  #pragma clang fp contract(off)
  float h[2];
  #pragma unroll
  for (int half = 0; half < 2; half++){
    const float* q = p + half * 128 * stride;
    float r[8];
    #pragma unroll
    for (int j = 0; j < 8; j++){ float z = q[j * stride]; r[j] = z * z; }
    for (int i = 8; i < 128; i += 8){
      #pragma unroll
      for (int j = 0; j < 8; j++){ float z = q[(i + j) * stride]; r[j] = r[j] + z * z; }
    }
    h[half] = ((r[0] + r[1]) + (r[2] + r[3])) + ((r[4] + r[5]) + (r[6] + r[7]));
  }
  return h[0] + h[1];
}

// ============ fused prep: {transpose + a32 single-pass} | cb->bf16 | b32 ============
// blocks [0,2048): x [B,C,H,W] -> flatB bf16 [token][c] AND a32 (x read ONCE).
// blocks [2048,4096): codebook fp32 -> bf16 (row-major, as k_dist stages it)
// blocks [4096,4128): b32 norms
__global__ void k_prep(const float* __restrict__ x, const float* __restrict__ cb,
                       unsigned short* __restrict__ flatB, unsigned short* __restrict__ cbB,
                       float* __restrict__ a32, float* __restrict__ b32)
{
  const int bx = blockIdx.x;
  const int t = threadIdx.x;
  if (bx < 2048){
    __shared__ float tile[256][17];
    const int b = bx >> 6, ht = bx & 63;
    const int hw0 = ht * 16;
    const int n0 = b * 1024 + hw0;
    const int wv = t >> 6, lane = t & 63;
    {
      const int cr = lane >> 2, hq = (lane & 3) * 4;
      #pragma unroll
      for (int j = 0; j < 4; j++){
        const int c = wv * 64 + j * 16 + cr;
        float4 v = *(const float4*)(x + ((size_t)(b * 256 + c) << 10) + hw0 + hq);
        tile[c][hq] = v.x; tile[c][hq+1] = v.y; tile[c][hq+2] = v.z; tile[c][hq+3] = v.w;
      }
    }
    __syncthreads();
    #pragma unroll
    for (int j = 0; j < 4; j++){
      const int tok = wv * 4 + j;
      ushort4 o = { f2b(tile[lane*4+0][tok]), f2b(tile[lane*4+1][tok]),
                    f2b(tile[lane*4+2][tok]), f2b(tile[lane*4+3][tok]) };
      *(ushort4*)(flatB + ((size_t)(n0 + tok) << 8) + lane * 4) = o;
    }
    if (t < 16){
      #pragma clang fp contract(off)
      float h[2];
      #pragma unroll
      for (int half = 0; half < 2; half++){
        float r[8];
        #pragma unroll
        for (int j = 0; j < 8; j++){ float z = tile[half*128 + j][t]; r[j] = z * z; }
        for (int i = 8; i < 128; i += 8){
          #pragma unroll
          for (int j = 0; j < 8; j++){ float z = tile[half*128 + i + j][t]; r[j] = r[j] + z * z; }
        }
        h[half] = ((r[0] + r[1]) + (r[2] + r[3])) + ((r[4] + r[5]) + (r[6] + r[7]));
      }
      a32[n0 + t] = h[0] + h[1];
    }
  } else if (bx < 4096){
    const int g = (bx - 2048) * 256 + t;    // 524,288
    float4 v = *(const float4*)(cb + (size_t)g * 4);
    ushort4 o = { f2b(v.x), f2b(v.y), f2b(v.z), f2b(v.w) };
    *(ushort4*)(cbB + (size_t)g * 4) = o;
  } else {
    const int g = (bx - 4096) * 256 + t;    // 8,192
    if (g < KCB) b32[g] = np_pairwise_sq(cb + (size_t)g * 256, 1);
  }
}

// ============ phase 1: bf16-MFMA distance GEMM + top-8 candidates/half ============
// Proven best variant (153.6us): 128x4096 tiles, 2-buffer B staging, barrier
// convoying gives near-perfect L2 reuse (FETCH ~24.7MB). Do not restructure:
// counted-vmcnt (r1), deep ring (r2), small tile (r6), barrier-free L2-direct
// (r7) all measured worse. The per-step barriers are load-bearing for L2
// locality (r7: without them, FETCH 949MB, 2.8x slower).
__launch_bounds__(256, 2)
__global__ void k_dist(const unsigned short* __restrict__ flatB,
                       const unsigned short* __restrict__ cbB,
                       const float* __restrict__ b32,
                       int* __restrict__ cand)
{
  __shared__ __align__(16) unsigned short A1[128 * 128];   // 32 KB: [row][k0..127]
  __shared__ __align__(16) unsigned short Bs[2][128 * 64]; // 2 x 16 KB

  const int tid = threadIdx.x;
  const int bx = blockIdx.x;             // 512 = 256 token-tiles x 2 halves
  const int tt = bx >> 1, h = bx & 1;
  const int tok0 = tt * 128;
  const int wv = tid >> 6, lane = tid & 63;
  const int wy = wv >> 1, wx = wv & 1;
  const int l4 = lane >> 4, lm = lane & 15;

  const unsigned short* fB = flatB + (size_t)tok0 * 256;
  const unsigned short* cB = cbB + (size_t)h * 4096 * 256;

  // ---- stage A1 (k 0..127) and A2 (k 128..255, into Bs region) ----
  {
    const int r = lane >> 4, p = lane & 15;
    #pragma unroll
    for (int j = 0; j < 8; j++){
      const int row = wv * 32 + j * 4 + r;
      const int gc = p ^ (row & 15);
      g2lds16((const char*)fB + (size_t)row * 512 + (gc << 4),
              (char*)A1 + (wv * 32 + j * 4) * 256);
    }
    unsigned short* A2 = &Bs[0][0];
    #pragma unroll
    for (int j = 0; j < 8; j++){
      const int row = wv * 32 + j * 4 + r;
      const int gc = p ^ (row & 15);
      g2lds16((const char*)fB + (size_t)row * 512 + 256 + (gc << 4),
              (char*)A2 + (wv * 32 + j * 4) * 256);
    }
  }
  __syncthreads();

  // ---- A k128..255 fragments -> registers (16 x b128 = 64 VGPR) ----
  bf16x8 a2[4][4];
  {
    const unsigned short* A2 = &Bs[0][0];
    #pragma unroll
    for (int ks4 = 0; ks4 < 4; ks4++)
      #pragma unroll
      for (int ii = 0; ii < 4; ii++){
        const int m = wy * 64 + ii * 16 + lm;
        const int c = ks4 * 4 + l4;
        a2[ks4][ii] = *(const bf16x8*)((const char*)A2 + m * 256 + ((c ^ (m & 15)) << 4));
      }
  }
  __syncthreads();   // A2 regs loaded; Bs region now reusable for B slices

  // ---- loop-invariant address precompute ----
  unsigned aoff[4][4];   // [kg 0..3][ii] byte offsets into A1
  #pragma unroll
  for (int kg = 0; kg < 4; kg++)
    #pragma unroll
    for (int ii = 0; ii < 4; ii++){
      const int m = wy * 64 + ii * 16 + lm;
      const int ca = kg * 4 + l4;
      aoff[kg][ii] = (unsigned)(m * 256 + ((ca ^ (m & 15)) << 4));
    }
  unsigned boff[2][2][4];  // [buf][ks2][jj] byte offsets into Bs
  #pragma unroll
  for (int buf = 0; buf < 2; buf++)
    #pragma unroll
    for (int ks2 = 0; ks2 < 2; ks2++)
      #pragma unroll
      for (int jj = 0; jj < 4; jj++){
        const int n = wx * 64 + jj * 16 + lm;
        const int c2 = ks2 * 4 + l4;
        boff[buf][ks2][jj] = (unsigned)(buf * 16384 + n * 128 + ((c2 ^ (n & 7)) << 4));
      }
  // stageB per-lane invariants
  const char* gBj[4];
  unsigned dstj[4];
  {
    const int r8 = lane >> 3, p = lane & 7;
    #pragma unroll
    for (int j = 0; j < 4; j++){
      const int row = wv * 32 + j * 8 + r8;
      const int gc = p ^ (row & 7);
      gBj[j] = (const char*)cB + (size_t)row * 512 + (gc << 4);
      dstj[j] = (unsigned)((wv * 32 + j * 8) * 128);
    }
  }

  auto stageB = [&](int S2){
    const int ss = S2 & 3, cc = S2 >> 2;
    const int buf = (S2 & 1) * 16384;
    const size_t soff = (size_t)(cc * 65536 + ss * 128);   // scalar (wave-uniform)
    #pragma unroll
    for (int j = 0; j < 4; j++)
      g2lds16(gBj[j] + soff, (char*)Bs + buf + dstj[j]);
  };

  unsigned k1[16], k2[16];
  #pragma unroll
  for (int i = 0; i < 16; i++){ k1[i] = 0xFFFFFFFFu; k2[i] = 0xFFFFFFFFu; }

  f32x4 acc[4][4];
  float bn125[4];

  stageB(0);
  __syncthreads();

  for (int c = 0; c < 32; c++){
    #pragma unroll
    for (int s = 0; s < 4; s++){
      const int S = c * 4 + s;
      if (S + 1 < 128) stageB(S + 1);
      if (s == 0){
        #pragma unroll
        for (int jj = 0; jj < 4; jj++)
          bn125[jj] = b32[h * 4096 + c * 128 + wx * 64 + jj * 16 + lm] + 0.125f;
        #pragma unroll
        for (int ii = 0; ii < 4; ii++)
          #pragma unroll
          for (int jj = 0; jj < 4; jj++)
            acc[ii][jj] = (f32x4){0.f, 0.f, 0.f, 0.f};
      }
      #pragma unroll
      for (int ks2 = 0; ks2 < 2; ks2++){
        const int kg = s * 2 + ks2;          // 0..7 (compile-time)
        bf16x8 bf[4], af[4];
        #pragma unroll
        for (int jj = 0; jj < 4; jj++)
          bf[jj] = *(const bf16x8*)((const char*)Bs + boff[s & 1][ks2][jj]);
        if (kg < 4){
          #pragma unroll
          for (int ii = 0; ii < 4; ii++)
            af[ii] = *(const bf16x8*)((const char*)A1 + aoff[kg][ii]);
        } else {
          #pragma unroll
          for (int ii = 0; ii < 4; ii++) af[ii] = a2[kg - 4][ii];
        }
        #pragma unroll
        for (int ii = 0; ii < 4; ii++)
          #pragma unroll
          for (int jj = 0; jj < 4; jj++)
            acc[ii][jj] = __builtin_amdgcn_mfma_f32_16x16x32_bf16(af[ii], bf[jj], acc[ii][jj], 0, 0, 0);
      }
      if (s == 3){
        // rank by float bits of (b - 2s + 0.125) > 0; (c<<2)|jj packed in low 7 bits
        unsigned pk[4];
        #pragma unroll
        for (int jj = 0; jj < 4; jj++) pk[jj] = (unsigned)((c << 2) | jj);
        #pragma unroll
        for (int ii = 0; ii < 4; ii++){
          #pragma unroll
          for (int r = 0; r < 4; r++){
            const int rk = ii * 4 + r;
            unsigned kb[4];
            #pragma unroll
            for (int jj = 0; jj < 4; jj++){
              const float v = fmaf(-2.f, acc[ii][jj][r], bn125[jj]);
              kb[jj] = (__float_as_uint(v) & 0xFFFFFF80u) | pk[jj];
            }
            // smallest-2-of-4
            const unsigned lo01 = umin2(kb[0], kb[1]), hi01 = umax2(kb[0], kb[1]);
            const unsigned lo23 = umin2(kb[2], kb[3]), hi23 = umax2(kb[2], kb[3]);
            const unsigned s1 = umin2(lo01, lo23);
            const unsigned s2 = umin2(umax2(lo01, lo23), umin2(hi01, hi23));
            // merge two sorted pairs (k1,k2) x (s1,s2) -> top-2
            const unsigned t = umax2(k1[rk], s1);
            k1[rk] = umin2(k1[rk], s1);
            k2[rk] = umin2(umin2(k2[rk], t), s2);
          }
        }
      }
      __syncthreads();
    }
  }

  // ---- finalize keys to (qi<<12)|col and merge: per row, top-8 of 64 keys ----
  const unsigned colbase = (unsigned)(wx * 64 + lm);
  auto fin = [colbase](unsigned key)->unsigned {
    const float v125 = __uint_as_float(key & 0xFFFFFF80u);
    int qi = (int)(v125 * 4194304.f);          // (v + 0.125) * 2^22
    qi = qi < 0 ? 0 : (qi > 0xFFFFF ? 0xFFFFF : qi);
    const unsigned cc = (key >> 2) & 31u, jj = key & 3u;
    return ((unsigned)qi << 12) | (cc * 128u + jj * 16u + colbase);
  };
  unsigned* red = (unsigned*)&A1[0];        // 32 KB = 8192 u32 = [128 rows][64]
  #pragma unroll
  for (int rk = 0; rk < 16; rk++){
    const int srow = wy * 64 + (rk >> 2) * 16 + l4 * 4 + (rk & 3);
    red[srow * 64 + wx * 32 + lm * 2 + 0] = fin(k1[rk]);
    red[srow * 64 + wx * 32 + lm * 2 + 1] = fin(k2[rk]);
  }
  __syncthreads();
  if (tid < 128){
    unsigned best[8];
    #pragma unroll
    for (int j = 0; j < 8; j++) best[j] = 0xFFFFFFFFu;
    for (int i = 0; i < 64; i++){
      unsigned k = red[tid * 64 + i];
      if (k < best[7]){
        best[7] = k;
        #pragma unroll
        for (int j = 7; j > 0; j--){
          if (best[j] < best[j-1]){ unsigned tmp = best[j]; best[j] = best[j-1]; best[j-1] = tmp; }
        }
      }
    }
    const size_t base = ((size_t)(tok0 + tid) * 2 + h) * 8;
    #pragma unroll
    for (int j = 0; j < 8; j++) cand[base + j] = h * 4096 + (int)(best[j] & 0xFFFu);
  }
}

// ========== phase 2: rescore + fused quantize/loss (16 lanes / token) ==========
__global__ void k_pick(const float* __restrict__ x, const float* __restrict__ cb,
                       const float* __restrict__ a32, const float* __restrict__ b32,
                       const int* __restrict__ cand, int* __restrict__ idx,
                       int* __restrict__ icnt, float* __restrict__ out_idx,
                       float* __restrict__ outq, double* __restrict__ lpart)
{
  __shared__ double wred[4];
  const int gt = blockIdx.x * 256 + threadIdx.x;
  const int wid = gt >> 6;                 // 0..8191
  const int lane = gt & 63;
  const int tq = lane & 3, cg = lane >> 2;
  const int n = wid * 4 + tq;              // token
  const int b = n >> 10, hw = n & 1023;

  const size_t xbase = (((size_t)(b * 256 + cg * 16)) << 10) + hw;
  float z[16];
  #pragma unroll
  for (int j = 0; j < 16; j++) z[j] = x[xbase + ((size_t)j << 10)];

  const float an = a32[n];
  float bestd = 3.4e38f; int besti = 0x7fffffff;
  for (int j = 0; j < 16; j++){
    const int ci = cand[(size_t)n * 16 + j];     // uniform across the 16 lanes
    if (ci < 0 || ci >= KCB) continue;
    const float* ep = cb + (size_t)ci * DIM + cg * 16;
    float4 e0 = *(const float4*)(ep + 0);
    float4 e1 = *(const float4*)(ep + 4);
    float4 e2 = *(const float4*)(ep + 8);
    float4 e3 = *(const float4*)(ep + 12);
    double se = (double)z[0]*e0.x + (double)z[1]*e0.y + (double)z[2]*e0.z + (double)z[3]*e0.w
              + (double)z[4]*e1.x + (double)z[5]*e1.y + (double)z[6]*e1.z + (double)z[7]*e1.w
              + (double)z[8]*e2.x + (double)z[9]*e2.y + (double)z[10]*e2.z + (double)z[11]*e2.w
              + (double)z[12]*e3.x + (double)z[13]*e3.y + (double)z[14]*e3.z + (double)z[15]*e3.w;
    se += __shfl_xor(se, 4, 64);
    se += __shfl_xor(se, 8, 64);
    se += __shfl_xor(se, 16, 64);
    se += __shfl_xor(se, 32, 64);
    const float A = an + b32[ci];
    const float d32 = (float)((double)A - 2.0 * se);
    if (d32 < bestd || (d32 == bestd && ci < besti)){ bestd = d32; besti = ci; }
  }

  // ---- fused quantize + loss ----
  double p = 0.0;
  {
    const float* ep = cb + (size_t)besti * DIM + cg * 16;
    float4 e0 = *(const float4*)(ep + 0);
    float4 e1 = *(const float4*)(ep + 4);
    float4 e2 = *(const float4*)(ep + 8);
    float4 e3 = *(const float4*)(ep + 12);
    float q[16] = { e0.x, e0.y, e0.z, e0.w, e1.x, e1.y, e1.z, e1.w,
                    e2.x, e2.y, e2.z, e2.w, e3.x, e3.y, e3.z, e3.w };
    #pragma unroll
    for (int j = 0; j < 16; j++){
      const float qd = q[j] - z[j];
      outq[xbase + ((size_t)j << 10)] = z[j] + qd;
      p += (double)(qd * qd);
    }
  }
  #pragma unroll
  for (int o = 32; o > 0; o >>= 1) p += __shfl_down(p, o, 64);
  if ((threadIdx.x & 63) == 0) wred[threadIdx.x >> 6] = p;

  if (cg == 0){
    idx[n] = besti;
    atomicAdd(icnt + besti, 1);
    out_idx[n] = (float)besti;
  }
  __syncthreads();
  if (threadIdx.x == 0) lpart[blockIdx.x] = (wred[0] + wred[1]) + (wred[2] + wred[3]);
}

// ========== bucket tokens by code (scan fused: each block scans icnt in LDS) ==========
__global__ void k_perm(const int* __restrict__ idx, const int* __restrict__ icnt,
                       int* __restrict__ cur, int* __restrict__ perm,
                       int* __restrict__ offs)
{
  __shared__ int offs_l[8192];
  __shared__ int sums[256];
  const int tid = threadIdx.x;
  int loc[32];
  int s = 0;
  #pragma unroll
  for (int i = 0; i < 32; i++){ loc[i] = s; s += icnt[tid * 32 + i]; }
  sums[tid] = s;
  #pragma unroll
  for (int off = 1; off < 256; off <<= 1){
    __syncthreads();
    const int add = (tid >= off) ? sums[tid - off] : 0;
    __syncthreads();
    sums[tid] += add;
  }
  __syncthreads();
  const int pre = (tid == 0) ? 0 : sums[tid - 1];
  #pragma unroll
  for (int i = 0; i < 32; i++) offs_l[tid * 32 + i] = pre + loc[i];
  if (blockIdx.x == 0){
    #pragma unroll
    for (int i = 0; i < 32; i++) offs[tid * 32 + i] = pre + loc[i];
  }
  __syncthreads();
  const int t = blockIdx.x * 256 + tid;        // 32,768
  const int code = idx[t];
  const int slot = atomicAdd(cur + code, 1);
  perm[offs_l[code] + slot] = t;
}

// ====== dw segment-sum + new_weight/new_codebook/new_count + e_loss (fused) ======
__global__ void k_dwf(const unsigned short* __restrict__ flatB,
                      const int* __restrict__ offs, const int* __restrict__ icnt,
                      const int* __restrict__ perm,
                      const float* __restrict__ ema_w, const float* __restrict__ ema_count,
                      const double* __restrict__ lpart, float* __restrict__ out)
{
  const int k = blockIdx.x;                   // 8192
  const int c = threadIdx.x;                  // 256
  const int start = offs[k], cnt = icnt[k];
  float s = 0.f;
  for (int i = 0; i < cnt; i++){
    const int n = perm[start + i];
    s += __uint_as_float(((unsigned)flatB[((size_t)n << 8) + c]) << 16);
  }
  // new_count (same exprs as before)
  float ct1 = ema_count[k] * 0.95f;
  float ct2 = 0.05f * (float)cnt;
  float sc  = ct1 + ct2;
  float sc2 = sc + 1e-5f;
  const float DEN = (float)(32768.0 + 8192.0 * 1e-5);
  float nc = (sc2 / DEN) * 32768.0f;
  if (c == 0) out[O_CNT + k] = nc;
  {
    #pragma clang fp contract(off)
    const int t = k * 256 + c;
    float w = ema_w[t];
    float t1 = w * 0.95f;
    float t2 = 0.05f * s;
    float nw = t1 + t2;        // np op order; bit-exact for empty codes (s==0)
    out[O_W + t]  = nw;
    out[O_CB + t] = nw / nc;
  }
  if (k == 0){
    __shared__ double sred[256];
    double ls = 0.0;
    for (int i = c; i < 2048; i += 256) ls += lpart[i];
    sred[c] = ls;
    __syncthreads();
    for (int off = 128; off > 0; off >>= 1){
      if (c < off) sred[c] += sred[c + off];
      __syncthreads();
    }
    if (c == 0) out[O_LOSS] = 0.25f * (float)(sred[0] / 8388608.0);
  }
}

// ===================== launch =====================
extern "C" void kernel_launch(void* const* d_in, const int* in_sizes, int n_in,
                              void* d_out, int out_size, void* d_ws, size_t ws_size,
                              hipStream_t stream)
{
  const float* x         = (const float*)d_in[0];
  const float* cb        = (const float*)d_in[1];
  const float* ema_count = (const float*)d_in[2];
  const float* ema_w     = (const float*)d_in[3];
  float* out = (float*)d_out;
  float* ws  = (float*)d_ws;

  unsigned short* flatB = (unsigned short*)(ws + WS_FLATB);
  unsigned short* cbB   = (unsigned short*)(ws + WS_CBB);
  float*  a32    = ws + WS_A32;
  float*  b32    = ws + WS_B32;
  int*    idxp   = (int*)(ws + WS_IDX);
  int*    candp  = (int*)(ws + WS_CAND);
  int*    icnt   = (int*)(ws + WS_ICNT);
  int*    curp   = (int*)(ws + WS_CUR);
  int*    offs   = (int*)(ws + WS_OFFS);
  int*    permp  = (int*)(ws + WS_PERM);
  double* lpart  = (double*)(ws + WS_LPART);

  (void)hipMemsetAsync(ws + WS_ICNT, 0, (size_t)WS_MEMSET_LEN * sizeof(float), stream);

  k_prep <<<4128, 256, 0, stream>>>(x, cb, flatB, cbB, a32, b32);
  k_dist <<<512,  256, 0, stream>>>(flatB, cbB, b32, candp);
  k_pick <<<2048, 256, 0, stream>>>(x, cb, a32, b32, candp, idxp, icnt,
                                    out + O_IDX, out + O_Q, lpart);
  k_perm <<<128,  256, 0, stream>>>(idxp, icnt, curp, permp, offs);
  k_dwf  <<<8192, 256, 0, stream>>>(flatB, offs, icnt, permp, ema_w, ema_count,
                                    lpart, out);
}

// Round 10
// 366.538 us; speedup vs baseline: 1.7803x; 1.0450x over previous
//
#include <hip/hip_runtime.h>
#include <stdint.h>

// Problem constants
#define N_TOK 32768   // B*H*W tokens
#define DIM   256
#define KCB   8192
#define HWSZ  1024

// ---- workspace layout (float offsets) ---- total 8,011,776 floats = 32.0 MB
#define WS_FLATB   0u          // bf16 flat [32768][256]  (4,194,304)
#define WS_CBB     4194304u    // bf16 cb [8192][256]     (1,048,576)
#define WS_A32     5242880u    // np-fp32 ||z||^2         32,768
#define WS_B32     5275648u    // np-fp32 ||e||^2         8,192
#define WS_IDX     5283840u    // argmin (int)            32,768
#define WS_CAND    5316608u    // [token][16] int         524,288
#define WS_ICNT    5840896u    // int histogram           8,192   <- memset from here
#define WS_CUR     5849088u    // int cursors             8,192   <- memset through here
#define WS_OFFS    5857280u    // int exclusive offsets   8,192
#define WS_PERM    5865472u    // int token permutation   32,768
#define WS_LPART   5898240u    // per-block loss partials 2,048 doubles (4,096 floats)
#define WS_TOTAL   8011776u
#define WS_MEMSET_LEN 16384u   // ICNT + CUR only

// ---- output layout (float offsets) ----
#define O_LOSS 0u
#define O_Q    1u
#define O_IDX  8388609u
#define O_CNT  8421377u
#define O_W    8429569u
#define O_CB   10526721u

typedef __attribute__((ext_vector_type(8))) short bf16x8;
typedef __attribute__((ext_vector_type(4))) float f32x4;

__device__ __forceinline__ void g2lds16(const void* gp, void* lp){
  __builtin_amdgcn_global_load_lds(
      (const __attribute__((address_space(1))) void*)gp,
      (__attribute__((address_space(3))) void*)lp, 16, 0, 0);
}

__device__ __forceinline__ unsigned short f2b(float f){   // fp32 -> bf16 RNE
  unsigned u = __float_as_uint(f);
  return (unsigned short)((u + 0x7FFFu + ((u >> 16) & 1u)) >> 16);
}

__device__ __forceinline__ unsigned umin2(unsigned a, unsigned b){ return a < b ? a : b; }
__device__ __forceinline__ unsigned umax2(unsigned a, unsigned b){ return a > b ? a : b; }

// ============ prep: squared norms, numpy pairwise fp32 order ============
__device__ __forceinline__ float np_pairwise_sq(const float* __restrict__ p, int stride){
  #pragma clang fp contract(off)
  float h[2];
  #pragma unroll
  for (int half = 0; half < 2; half++){
    const float* q = p + half * 128 * stride;
    float r[8];
    #pragma unroll
    for (int j = 0; j < 8; j++){ float z = q[j * stride]; r[j] = z * z; }
    for (int i = 8; i < 128; i += 8){
      #pragma unroll
      for (int j = 0; j < 8; j++){ float z = q[(i + j) * stride]; r[j] = r[j] + z * z; }
    }
    h[half] = ((r[0] + r[1]) + (r[2] + r[3])) + ((r[4] + r[5]) + (r[6] + r[7]));
  }
  return h[0] + h[1];
}

// ============ fused prep: {transpose + a32 single-pass} | cb->bf16 | b32 ============
__global__ void k_prep(const float* __restrict__ x, const float* __restrict__ cb,
                       unsigned short* __restrict__ flatB, unsigned short* __restrict__ cbB,
                       float* __restrict__ a32, float* __restrict__ b32)
{
  const int bx = blockIdx.x;
  const int t = threadIdx.x;
  if (bx < 2048){
    __shared__ float tile[256][17];
    const int b = bx >> 6, ht = bx & 63;
    const int hw0 = ht * 16;
    const int n0 = b * 1024 + hw0;
    const int wv = t >> 6, lane = t & 63;
    {
      const int cr = lane >> 2, hq = (lane & 3) * 4;
      #pragma unroll
      for (int j = 0; j < 4; j++){
        const int c = wv * 64 + j * 16 + cr;
        float4 v = *(const float4*)(x + ((size_t)(b * 256 + c) << 10) + hw0 + hq);
        tile[c][hq] = v.x; tile[c][hq+1] = v.y; tile[c][hq+2] = v.z; tile[c][hq+3] = v.w;
      }
    }
    __syncthreads();
    #pragma unroll
    for (int j = 0; j < 4; j++){
      const int tok = wv * 4 + j;
      ushort4 o = { f2b(tile[lane*4+0][tok]), f2b(tile[lane*4+1][tok]),
                    f2b(tile[lane*4+2][tok]), f2b(tile[lane*4+3][tok]) };
      *(ushort4*)(flatB + ((size_t)(n0 + tok) << 8) + lane * 4) = o;
    }
    if (t < 16){
      #pragma clang fp contract(off)
      float h[2];
      #pragma unroll
      for (int half = 0; half < 2; half++){
        float r[8];
        #pragma unroll
        for (int j = 0; j < 8; j++){ float z = tile[half*128 + j][t]; r[j] = z * z; }
        for (int i = 8; i < 128; i += 8){
          #pragma unroll
          for (int j = 0; j < 8; j++){ float z = tile[half*128 + i + j][t]; r[j] = r[j] + z * z; }
        }
        h[half] = ((r[0] + r[1]) + (r[2] + r[3])) + ((r[4] + r[5]) + (r[6] + r[7]));
      }
      a32[n0 + t] = h[0] + h[1];
    }
  } else if (bx < 4096){
    const int g = (bx - 2048) * 256 + t;    // 524,288
    float4 v = *(const float4*)(cb + (size_t)g * 4);
    ushort4 o = { f2b(v.x), f2b(v.y), f2b(v.z), f2b(v.w) };
    *(ushort4*)(cbB + (size_t)g * 4) = o;
  } else {
    const int g = (bx - 4096) * 256 + t;    // 8,192
    if (g < KCB) b32[g] = np_pairwise_sq(cb + (size_t)g * 256, 1);
  }
}

// ============ phase 1: bf16-MFMA distance GEMM + top-8 candidates/half ============
// Proven best variant (~155us): 128x4096 tiles, 2-buffer B staging, barrier
// convoying gives near-perfect L2 reuse (FETCH ~24.7MB). Do not restructure:
// counted-vmcnt (r1), deep ring (r2), small tile (r6), barrier-free L2-direct
// (r7) all measured worse. The per-step barriers are load-bearing for L2
// locality (r7: without them, FETCH 949MB, 2.8x slower).
__launch_bounds__(256, 2)
__global__ void k_dist(const unsigned short* __restrict__ flatB,
                       const unsigned short* __restrict__ cbB,
                       const float* __restrict__ b32,
                       int* __restrict__ cand)
{
  __shared__ __align__(16) unsigned short A1[128 * 128];   // 32 KB: [row][k0..127]
  __shared__ __align__(16) unsigned short Bs[2][128 * 64]; // 2 x 16 KB

  const int tid = threadIdx.x;
  const int bx = blockIdx.x;             // 512 = 256 token-tiles x 2 halves
  const int tt = bx >> 1, h = bx & 1;
  const int tok0 = tt * 128;
  const int wv = tid >> 6, lane = tid & 63;
  const int wy = wv >> 1, wx = wv & 1;
  const int l4 = lane >> 4, lm = lane & 15;

  const unsigned short* fB = flatB + (size_t)tok0 * 256;
  const unsigned short* cB = cbB + (size_t)h * 4096 * 256;

  // ---- stage A1 (k 0..127) and A2 (k 128..255, into Bs region) ----
  {
    const int r = lane >> 4, p = lane & 15;
    #pragma unroll
    for (int j = 0; j < 8; j++){
      const int row = wv * 32 + j * 4 + r;
      const int gc = p ^ (row & 15);
      g2lds16((const char*)fB + (size_t)row * 512 + (gc << 4),
              (char*)A1 + (wv * 32 + j * 4) * 256);
    }
    unsigned short* A2 = &Bs[0][0];
    #pragma unroll
    for (int j = 0; j < 8; j++){
      const int row = wv * 32 + j * 4 + r;
      const int gc = p ^ (row & 15);
      g2lds16((const char*)fB + (size_t)row * 512 + 256 + (gc << 4),
              (char*)A2 + (wv * 32 + j * 4) * 256);
    }
  }
  __syncthreads();

  // ---- A k128..255 fragments -> registers (16 x b128 = 64 VGPR) ----
  bf16x8 a2[4][4];
  {
    const unsigned short* A2 = &Bs[0][0];
    #pragma unroll
    for (int ks4 = 0; ks4 < 4; ks4++)
      #pragma unroll
      for (int ii = 0; ii < 4; ii++){
        const int m = wy * 64 + ii * 16 + lm;
        const int c = ks4 * 4 + l4;
        a2[ks4][ii] = *(const bf16x8*)((const char*)A2 + m * 256 + ((c ^ (m & 15)) << 4));
      }
  }
  __syncthreads();   // A2 regs loaded; Bs region now reusable for B slices

  // ---- loop-invariant address precompute ----
  unsigned aoff[4][4];   // [kg 0..3][ii] byte offsets into A1
  #pragma unroll
  for (int kg = 0; kg < 4; kg++)
    #pragma unroll
    for (int ii = 0; ii < 4; ii++){
      const int m = wy * 64 + ii * 16 + lm;
      const int ca = kg * 4 + l4;
      aoff[kg][ii] = (unsigned)(m * 256 + ((ca ^ (m & 15)) << 4));
    }
  unsigned boff[2][2][4];  // [buf][ks2][jj] byte offsets into Bs
  #pragma unroll
  for (int buf = 0; buf < 2; buf++)
    #pragma unroll
    for (int ks2 = 0; ks2 < 2; ks2++)
      #pragma unroll
      for (int jj = 0; jj < 4; jj++){
        const int n = wx * 64 + jj * 16 + lm;
        const int c2 = ks2 * 4 + l4;
        boff[buf][ks2][jj] = (unsigned)(buf * 16384 + n * 128 + ((c2 ^ (n & 7)) << 4));
      }
  // stageB per-lane invariants
  const char* gBj[4];
  unsigned dstj[4];
  {
    const int r8 = lane >> 3, p = lane & 7;
    #pragma unroll
    for (int j = 0; j < 4; j++){
      const int row = wv * 32 + j * 8 + r8;
      const int gc = p ^ (row & 7);
      gBj[j] = (const char*)cB + (size_t)row * 512 + (gc << 4);
      dstj[j] = (unsigned)((wv * 32 + j * 8) * 128);
    }
  }

  auto stageB = [&](int S2){
    const int ss = S2 & 3, cc = S2 >> 2;
    const int buf = (S2 & 1) * 16384;
    const size_t soff = (size_t)(cc * 65536 + ss * 128);   // scalar (wave-uniform)
    #pragma unroll
    for (int j = 0; j < 4; j++)
      g2lds16(gBj[j] + soff, (char*)Bs + buf + dstj[j]);
  };

  unsigned k1[16], k2[16];
  #pragma unroll
  for (int i = 0; i < 16; i++){ k1[i] = 0xFFFFFFFFu; k2[i] = 0xFFFFFFFFu; }

  f32x4 acc[4][4];
  float bn125[4];

  stageB(0);
  __syncthreads();

  for (int c = 0; c < 32; c++){
    #pragma unroll
    for (int s = 0; s < 4; s++){
      const int S = c * 4 + s;
      if (S + 1 < 128) stageB(S + 1);
      if (s == 0){
        #pragma unroll
        for (int jj = 0; jj < 4; jj++)
          bn125[jj] = b32[h * 4096 + c * 128 + wx * 64 + jj * 16 + lm] + 0.125f;
        #pragma unroll
        for (int ii = 0; ii < 4; ii++)
          #pragma unroll
          for (int jj = 0; jj < 4; jj++)
            acc[ii][jj] = (f32x4){0.f, 0.f, 0.f, 0.f};
      }
      #pragma unroll
      for (int ks2 = 0; ks2 < 2; ks2++){
        const int kg = s * 2 + ks2;          // 0..7 (compile-time)
        bf16x8 bf[4], af[4];
        #pragma unroll
        for (int jj = 0; jj < 4; jj++)
          bf[jj] = *(const bf16x8*)((const char*)Bs + boff[s & 1][ks2][jj]);
        if (kg < 4){
          #pragma unroll
          for (int ii = 0; ii < 4; ii++)
            af[ii] = *(const bf16x8*)((const char*)A1 + aoff[kg][ii]);
        } else {
          #pragma unroll
          for (int ii = 0; ii < 4; ii++) af[ii] = a2[kg - 4][ii];
        }
        #pragma unroll
        for (int ii = 0; ii < 4; ii++)
          #pragma unroll
          for (int jj = 0; jj < 4; jj++)
            acc[ii][jj] = __builtin_amdgcn_mfma_f32_16x16x32_bf16(af[ii], bf[jj], acc[ii][jj], 0, 0, 0);
      }
      if (s == 3){
        // rank by float bits of (b - 2s + 0.125) > 0; (c<<2)|jj packed in low 7 bits
        unsigned pk[4];
        #pragma unroll
        for (int jj = 0; jj < 4; jj++) pk[jj] = (unsigned)((c << 2) | jj);
        #pragma unroll
        for (int ii = 0; ii < 4; ii++){
          #pragma unroll
          for (int r = 0; r < 4; r++){
            const int rk = ii * 4 + r;
            unsigned kb[4];
            #pragma unroll
            for (int jj = 0; jj < 4; jj++){
              const float v = fmaf(-2.f, acc[ii][jj][r], bn125[jj]);
              kb[jj] = (__float_as_uint(v) & 0xFFFFFF80u) | pk[jj];
            }
            // smallest-2-of-4
            const unsigned lo01 = umin2(kb[0], kb[1]), hi01 = umax2(kb[0], kb[1]);
            const unsigned lo23 = umin2(kb[2], kb[3]), hi23 = umax2(kb[2], kb[3]);
            const unsigned s1 = umin2(lo01, lo23);
            const unsigned s2 = umin2(umax2(lo01, lo23), umin2(hi01, hi23));
            // merge two sorted pairs (k1,k2) x (s1,s2) -> top-2
            const unsigned t = umax2(k1[rk], s1);
            k1[rk] = umin2(k1[rk], s1);
            k2[rk] = umin2(umin2(k2[rk], t), s2);
          }
        }
      }
      __syncthreads();
    }
  }

  // ---- finalize keys to (qi<<12)|col and merge: per row, top-8 of 64 keys ----
  const unsigned colbase = (unsigned)(wx * 64 + lm);
  auto fin = [colbase](unsigned key)->unsigned {
    const float v125 = __uint_as_float(key & 0xFFFFFF80u);
    int qi = (int)(v125 * 4194304.f);          // (v + 0.125) * 2^22
    qi = qi < 0 ? 0 : (qi > 0xFFFFF ? 0xFFFFF : qi);
    const unsigned cc = (key >> 2) & 31u, jj = key & 3u;
    return ((unsigned)qi << 12) | (cc * 128u + jj * 16u + colbase);
  };
  unsigned* red = (unsigned*)&A1[0];        // 32 KB = 8192 u32 = [128 rows][64]
  #pragma unroll
  for (int rk = 0; rk < 16; rk++){
    const int srow = wy * 64 + (rk >> 2) * 16 + l4 * 4 + (rk & 3);
    red[srow * 64 + wx * 32 + lm * 2 + 0] = fin(k1[rk]);
    red[srow * 64 + wx * 32 + lm * 2 + 1] = fin(k2[rk]);
  }
  __syncthreads();
  if (tid < 128){
    unsigned best[8];
    #pragma unroll
    for (int j = 0; j < 8; j++) best[j] = 0xFFFFFFFFu;
    for (int i = 0; i < 64; i++){
      unsigned k = red[tid * 64 + i];
      if (k < best[7]){
        best[7] = k;
        #pragma unroll
        for (int j = 7; j > 0; j--){
          if (best[j] < best[j-1]){ unsigned tmp = best[j]; best[j] = best[j-1]; best[j-1] = tmp; }
        }
      }
    }
    const size_t base = ((size_t)(tok0 + tid) * 2 + h) * 8;
    #pragma unroll
    for (int j = 0; j < 8; j++) cand[base + j] = h * 4096 + (int)(best[j] & 0xFFFu);
  }
}

// ========== phase 2: rescore + fused quantize/loss, LDS-tiled x/outq ==========
// Block = 16 consecutive tokens (same b). x[b,:,hw0..hw0+15] staged to LDS with
// 64B-per-row coalesced reads (4x better granularity than the previous per-token
// 16B scatter); outq written back the same way. The rescore math is UNCHANGED:
// identical lane->(token, channel-group) mapping (wave wv, tq=lane&3, cg=lane>>2
// covers token bx*16+wv*4+tq, channels cg*16+j), identical double-dot order,
// identical butterfly masks, identical wred/lpart summation order. Each LDS cell
// (c, t) is read/written only by its owner lane, so in-place quantize is
// race-free; one barrier before the cooperative write-out.
__global__ void k_pick(const float* __restrict__ x, const float* __restrict__ cb,
                       const float* __restrict__ a32, const float* __restrict__ b32,
                       const int* __restrict__ cand, int* __restrict__ idx,
                       int* __restrict__ icnt, float* __restrict__ out_idx,
                       float* __restrict__ outq, double* __restrict__ lpart)
{
  __shared__ float xt[256][17];
  __shared__ double wred[4];
  const int tid = threadIdx.x;
  const int bx = blockIdx.x;              // 2048 blocks x 16 tokens
  const int n0 = bx * 16;
  const int b = n0 >> 10, hw0 = n0 & 1023;
  const int wv = tid >> 6, lane = tid & 63;

  // ---- stage x[b, :, hw0..hw0+15] -> xt (64B-granule reads) ----
  {
    const int cr = lane >> 2, hq = (lane & 3) * 4;
    #pragma unroll
    for (int j = 0; j < 4; j++){
      const int c = wv * 64 + j * 16 + cr;
      float4 v = *(const float4*)(x + ((size_t)(b * 256 + c) << 10) + hw0 + hq);
      xt[c][hq] = v.x; xt[c][hq+1] = v.y; xt[c][hq+2] = v.z; xt[c][hq+3] = v.w;
    }
  }
  __syncthreads();

  const int tq = lane & 3, cg = lane >> 2;
  const int tl = wv * 4 + tq;             // token-local 0..15
  const int n = n0 + tl;

  float z[16];
  #pragma unroll
  for (int j = 0; j < 16; j++) z[j] = xt[cg * 16 + j][tl];

  const float an = a32[n];
  float bestd = 3.4e38f; int besti = 0x7fffffff;
  for (int j = 0; j < 16; j++){
    const int ci = cand[(size_t)n * 16 + j];     // uniform across the 16 lanes
    if (ci < 0 || ci >= KCB) continue;
    const float* ep = cb + (size_t)ci * DIM + cg * 16;
    float4 e0 = *(const float4*)(ep + 0);
    float4 e1 = *(const float4*)(ep + 4);
    float4 e2 = *(const float4*)(ep + 8);
    float4 e3 = *(const float4*)(ep + 12);
    double se = (double)z[0]*e0.x + (double)z[1]*e0.y + (double)z[2]*e0.z + (double)z[3]*e0.w
              + (double)z[4]*e1.x + (double)z[5]*e1.y + (double)z[6]*e1.z + (double)z[7]*e1.w
              + (double)z[8]*e2.x + (double)z[9]*e2.y + (double)z[10]*e2.z + (double)z[11]*e2.w
              + (double)z[12]*e3.x + (double)z[13]*e3.y + (double)z[14]*e3.z + (double)z[15]*e3.w;
    se += __shfl_xor(se, 4, 64);
    se += __shfl_xor(se, 8, 64);
    se += __shfl_xor(se, 16, 64);
    se += __shfl_xor(se, 32, 64);
    const float A = an + b32[ci];
    const float d32 = (float)((double)A - 2.0 * se);
    if (d32 < bestd || (d32 == bestd && ci < besti)){ bestd = d32; besti = ci; }
  }

  // ---- fused quantize (in place into xt) + loss ----
  double p = 0.0;
  {
    const float* ep = cb + (size_t)besti * DIM + cg * 16;
    float4 e0 = *(const float4*)(ep + 0);
    float4 e1 = *(const float4*)(ep + 4);
    float4 e2 = *(const float4*)(ep + 8);
    float4 e3 = *(const float4*)(ep + 12);
    float q[16] = { e0.x, e0.y, e0.z, e0.w, e1.x, e1.y, e1.z, e1.w,
                    e2.x, e2.y, e2.z, e2.w, e3.x, e3.y, e3.z, e3.w };
    #pragma unroll
    for (int j = 0; j < 16; j++){
      const float qd = q[j] - z[j];
      xt[cg * 16 + j][tl] = z[j] + qd;
      p += (double)(qd * qd);
    }
  }
  #pragma unroll
  for (int o = 32; o > 0; o >>= 1) p += __shfl_down(p, o, 64);
  if ((tid & 63) == 0) wred[tid >> 6] = p;

  if (cg == 0){
    idx[n] = besti;
    atomicAdd(icnt + besti, 1);
    out_idx[n] = (float)besti;
  }
  __syncthreads();

  // ---- write outq (64B-granule writes) ----
  {
    const int cr = lane >> 2, hq = (lane & 3) * 4;
    #pragma unroll
    for (int j = 0; j < 4; j++){
      const int c = wv * 64 + j * 16 + cr;
      float4 v = { xt[c][hq], xt[c][hq+1], xt[c][hq+2], xt[c][hq+3] };
      *(float4*)(outq + ((size_t)(b * 256 + c) << 10) + hw0 + hq) = v;
    }
  }
  if (tid == 0) lpart[bx] = (wred[0] + wred[1]) + (wred[2] + wred[3]);
}

// ========== bucket tokens by code (scan fused: each block scans icnt in LDS) ==========
__global__ void k_perm(const int* __restrict__ idx, const int* __restrict__ icnt,
                       int* __restrict__ cur, int* __restrict__ perm,
                       int* __restrict__ offs)
{
  __shared__ int offs_l[8192];
  __shared__ int sums[256];
  const int tid = threadIdx.x;
  int loc[32];
  int s = 0;
  #pragma unroll
  for (int i = 0; i < 32; i++){ loc[i] = s; s += icnt[tid * 32 + i]; }
  sums[tid] = s;
  #pragma unroll
  for (int off = 1; off < 256; off <<= 1){
    __syncthreads();
    const int add = (tid >= off) ? sums[tid - off] : 0;
    __syncthreads();
    sums[tid] += add;
  }
  __syncthreads();
  const int pre = (tid == 0) ? 0 : sums[tid - 1];
  #pragma unroll
  for (int i = 0; i < 32; i++) offs_l[tid * 32 + i] = pre + loc[i];
  if (blockIdx.x == 0){
    #pragma unroll
    for (int i = 0; i < 32; i++) offs[tid * 32 + i] = pre + loc[i];
  }
  __syncthreads();
  const int t = blockIdx.x * 256 + tid;        // 32,768
  const int code = idx[t];
  const int slot = atomicAdd(cur + code, 1);
  perm[offs_l[code] + slot] = t;
}

// ====== dw segment-sum + new_weight/new_codebook/new_count + e_loss (fused) ======
__global__ void k_dwf(const unsigned short* __restrict__ flatB,
                      const int* __restrict__ offs, const int* __restrict__ icnt,
                      const int* __restrict__ perm,
                      const float* __restrict__ ema_w, const float* __restrict__ ema_count,
                      const double* __restrict__ lpart, float* __restrict__ out)
{
  const int k = blockIdx.x;                   // 8192
  const int c = threadIdx.x;                  // 256
  const int start = offs[k], cnt = icnt[k];
  float s = 0.f;
  for (int i = 0; i < cnt; i++){
    const int n = perm[start + i];
    s += __uint_as_float(((unsigned)flatB[((size_t)n << 8) + c]) << 16);
  }
  // new_count (same exprs as before)
  float ct1 = ema_count[k] * 0.95f;
  float ct2 = 0.05f * (float)cnt;
  float sc  = ct1 + ct2;
  float sc2 = sc + 1e-5f;
  const float DEN = (float)(32768.0 + 8192.0 * 1e-5);
  float nc = (sc2 / DEN) * 32768.0f;
  if (c == 0) out[O_CNT + k] = nc;
  {
    #pragma clang fp contract(off)
    const int t = k * 256 + c;
    float w = ema_w[t];
    float t1 = w * 0.95f;
    float t2 = 0.05f * s;
    float nw = t1 + t2;        // np op order; bit-exact for empty codes (s==0)
    out[O_W + t]  = nw;
    out[O_CB + t] = nw / nc;
  }
  if (k == 0){
    __shared__ double sred[256];
    double ls = 0.0;
    for (int i = c; i < 2048; i += 256) ls += lpart[i];
    sred[c] = ls;
    __syncthreads();
    for (int off = 128; off > 0; off >>= 1){
      if (c < off) sred[c] += sred[c + off];
      __syncthreads();
    }
    if (c == 0) out[O_LOSS] = 0.25f * (float)(sred[0] / 8388608.0);
  }
}

// ===================== launch =====================
extern "C" void kernel_launch(void* const* d_in, const int* in_sizes, int n_in,
                              void* d_out, int out_size, void* d_ws, size_t ws_size,
                              hipStream_t stream)
{
  const float* x         = (const float*)d_in[0];
  const float* cb        = (const float*)d_in[1];
  const float* ema_count = (const float*)d_in[2];
  const float* ema_w     = (const float*)d_in[3];
  float* out = (float*)d_out;
  float* ws  = (float*)d_ws;

  unsigned short* flatB = (unsigned short*)(ws + WS_FLATB);
  unsigned short* cbB   = (unsigned short*)(ws + WS_CBB);
  float*  a32    = ws + WS_A32;
  float*  b32    = ws + WS_B32;
  int*    idxp   = (int*)(ws + WS_IDX);
  int*    candp  = (int*)(ws + WS_CAND);
  int*    icnt   = (int*)(ws + WS_ICNT);
  int*    curp   = (int*)(ws + WS_CUR);
  int*    offs   = (int*)(ws + WS_OFFS);
  int*    permp  = (int*)(ws + WS_PERM);
  double* lpart  = (double*)(ws + WS_LPART);

  (void)hipMemsetAsync(ws + WS_ICNT, 0, (size_t)WS_MEMSET_LEN * sizeof(float), stream);

  k_prep <<<4128, 256, 0, stream>>>(x, cb, flatB, cbB, a32, b32);
  k_dist <<<512,  256, 0, stream>>>(flatB, cbB, b32, candp);
  k_pick <<<2048, 256, 0, stream>>>(x, cb, a32, b32, candp, idxp, icnt,
                                    out + O_IDX, out + O_Q, lpart);
  k_perm <<<128,  256, 0, stream>>>(idxp, icnt, curp, permp, offs);
  k_dwf  <<<8192, 256, 0, stream>>>(flatB, offs, icnt, permp, ema_w, ema_count,
                                    lpart, out);
}

// Round 11
// 363.333 us; speedup vs baseline: 1.7960x; 1.0088x over previous
//
#include <hip/hip_runtime.h>
#include <stdint.h>

// Problem constants
#define N_TOK 32768   // B*H*W tokens
#define DIM   256
#define KCB   8192
#define HWSZ  1024

// ---- workspace layout (float offsets) ---- total 8,011,776 floats = 32.0 MB
#define WS_FLATB   0u          // bf16 flat [32768][256]  (4,194,304)
#define WS_CBB     4194304u    // bf16 cb [8192][256]     (1,048,576)
#define WS_A32     5242880u    // np-fp32 ||z||^2         32,768
#define WS_B32     5275648u    // np-fp32 ||e||^2         8,192
#define WS_IDX     5283840u    // argmin (int)            32,768
#define WS_CAND    5316608u    // [token][16] int         524,288
#define WS_ICNT    5840896u    // int histogram           8,192   <- zeroed in k_prep
#define WS_CUR     5849088u    // int cursors             8,192   <- zeroed in k_prep
#define WS_OFFS    5857280u    // int exclusive offsets   8,192
#define WS_PERM    5865472u    // int token permutation   32,768
#define WS_LPART   5898240u    // per-block loss partials 2,048 doubles (4,096 floats)
#define WS_TOTAL   8011776u

// ---- output layout (float offsets) ----
#define O_LOSS 0u
#define O_Q    1u
#define O_IDX  8388609u
#define O_CNT  8421377u
#define O_W    8429569u
#define O_CB   10526721u

typedef __attribute__((ext_vector_type(8))) short bf16x8;
typedef __attribute__((ext_vector_type(4))) float f32x4;

__device__ __forceinline__ void g2lds16(const void* gp, void* lp){
  __builtin_amdgcn_global_load_lds(
      (const __attribute__((address_space(1))) void*)gp,
      (__attribute__((address_space(3))) void*)lp, 16, 0, 0);
}

__device__ __forceinline__ unsigned short f2b(float f){   // fp32 -> bf16 RNE
  unsigned u = __float_as_uint(f);
  return (unsigned short)((u + 0x7FFFu + ((u >> 16) & 1u)) >> 16);
}

__device__ __forceinline__ unsigned umin2(unsigned a, unsigned b){ return a < b ? a : b; }
__device__ __forceinline__ unsigned umax2(unsigned a, unsigned b){ return a > b ? a : b; }

// ============ prep: squared norms, numpy pairwise fp32 order ============
__device__ __forceinline__ float np_pairwise_sq(const float* __restrict__ p, int stride){
  #pragma clang fp contract(off)
  float h[2];
  #pragma unroll
  for (int half = 0; half < 2; half++){
    const float* q = p + half * 128 * stride;
    float r[8];
    #pragma unroll
    for (int j = 0; j < 8; j++){ float z = q[j * stride]; r[j] = z * z; }
    for (int i = 8; i < 128; i += 8){
      #pragma unroll
      for (int j = 0; j < 8; j++){ float z = q[(i + j) * stride]; r[j] = r[j] + z * z; }
    }
    h[half] = ((r[0] + r[1]) + (r[2] + r[3])) + ((r[4] + r[5]) + (r[6] + r[7]));
  }
  return h[0] + h[1];
}

// ============ fused prep: {transpose + a32} | cb->bf16 | b32 + zero icnt/cur ============
__global__ void k_prep(const float* __restrict__ x, const float* __restrict__ cb,
                       unsigned short* __restrict__ flatB, unsigned short* __restrict__ cbB,
                       float* __restrict__ a32, float* __restrict__ b32,
                       int* __restrict__ icnt, int* __restrict__ cur)
{
  const int bx = blockIdx.x;
  const int t = threadIdx.x;
  if (bx < 2048){
    __shared__ float tile[256][17];
    const int b = bx >> 6, ht = bx & 63;
    const int hw0 = ht * 16;
    const int n0 = b * 1024 + hw0;
    const int wv = t >> 6, lane = t & 63;
    {
      const int cr = lane >> 2, hq = (lane & 3) * 4;
      #pragma unroll
      for (int j = 0; j < 4; j++){
        const int c = wv * 64 + j * 16 + cr;
        float4 v = *(const float4*)(x + ((size_t)(b * 256 + c) << 10) + hw0 + hq);
        tile[c][hq] = v.x; tile[c][hq+1] = v.y; tile[c][hq+2] = v.z; tile[c][hq+3] = v.w;
      }
    }
    __syncthreads();
    #pragma unroll
    for (int j = 0; j < 4; j++){
      const int tok = wv * 4 + j;
      ushort4 o = { f2b(tile[lane*4+0][tok]), f2b(tile[lane*4+1][tok]),
                    f2b(tile[lane*4+2][tok]), f2b(tile[lane*4+3][tok]) };
      *(ushort4*)(flatB + ((size_t)(n0 + tok) << 8) + lane * 4) = o;
    }
    if (t < 16){
      #pragma clang fp contract(off)
      float h[2];
      #pragma unroll
      for (int half = 0; half < 2; half++){
        float r[8];
        #pragma unroll
        for (int j = 0; j < 8; j++){ float z = tile[half*128 + j][t]; r[j] = z * z; }
        for (int i = 8; i < 128; i += 8){
          #pragma unroll
          for (int j = 0; j < 8; j++){ float z = tile[half*128 + i + j][t]; r[j] = r[j] + z * z; }
        }
        h[half] = ((r[0] + r[1]) + (r[2] + r[3])) + ((r[4] + r[5]) + (r[6] + r[7]));
      }
      a32[n0 + t] = h[0] + h[1];
    }
  } else if (bx < 4096){
    const int g = (bx - 2048) * 256 + t;    // 524,288
    float4 v = *(const float4*)(cb + (size_t)g * 4);
    ushort4 o = { f2b(v.x), f2b(v.y), f2b(v.z), f2b(v.w) };
    *(ushort4*)(cbB + (size_t)g * 4) = o;
  } else {
    const int g = (bx - 4096) * 256 + t;    // 8,192
    if (g < KCB){
      b32[g] = np_pairwise_sq(cb + (size_t)g * 256, 1);
      icnt[g] = 0;                          // replaces hipMemsetAsync
      cur[g]  = 0;
    }
  }
}

// ============ phase 1: bf16-MFMA distance GEMM + top-8 candidates/half ============
// Proven best variant (~155us): 128x4096 tiles, 2-buffer B staging, barrier
// convoying gives near-perfect L2 reuse (FETCH ~24.7MB). Do not restructure:
// counted-vmcnt (r1), deep ring (r2), small tile (r6), barrier-free L2-direct
// (r7) all measured worse. The per-step barriers are load-bearing for L2
// locality (r7: without them, FETCH 949MB, 2.8x slower).
__launch_bounds__(256, 2)
__global__ void k_dist(const unsigned short* __restrict__ flatB,
                       const unsigned short* __restrict__ cbB,
                       const float* __restrict__ b32,
                       int* __restrict__ cand)
{
  __shared__ __align__(16) unsigned short A1[128 * 128];   // 32 KB: [row][k0..127]
  __shared__ __align__(16) unsigned short Bs[2][128 * 64]; // 2 x 16 KB

  const int tid = threadIdx.x;
  const int bx = blockIdx.x;             // 512 = 256 token-tiles x 2 halves
  const int tt = bx >> 1, h = bx & 1;
  const int tok0 = tt * 128;
  const int wv = tid >> 6, lane = tid & 63;
  const int wy = wv >> 1, wx = wv & 1;
  const int l4 = lane >> 4, lm = lane & 15;

  const unsigned short* fB = flatB + (size_t)tok0 * 256;
  const unsigned short* cB = cbB + (size_t)h * 4096 * 256;

  // ---- stage A1 (k 0..127) and A2 (k 128..255, into Bs region) ----
  {
    const int r = lane >> 4, p = lane & 15;
    #pragma unroll
    for (int j = 0; j < 8; j++){
      const int row = wv * 32 + j * 4 + r;
      const int gc = p ^ (row & 15);
      g2lds16((const char*)fB + (size_t)row * 512 + (gc << 4),
              (char*)A1 + (wv * 32 + j * 4) * 256);
    }
    unsigned short* A2 = &Bs[0][0];
    #pragma unroll
    for (int j = 0; j < 8; j++){
      const int row = wv * 32 + j * 4 + r;
      const int gc = p ^ (row & 15);
      g2lds16((const char*)fB + (size_t)row * 512 + 256 + (gc << 4),
              (char*)A2 + (wv * 32 + j * 4) * 256);
    }
  }
  __syncthreads();

  // ---- A k128..255 fragments -> registers (16 x b128 = 64 VGPR) ----
  bf16x8 a2[4][4];
  {
    const unsigned short* A2 = &Bs[0][0];
    #pragma unroll
    for (int ks4 = 0; ks4 < 4; ks4++)
      #pragma unroll
      for (int ii = 0; ii < 4; ii++){
        const int m = wy * 64 + ii * 16 + lm;
        const int c = ks4 * 4 + l4;
        a2[ks4][ii] = *(const bf16x8*)((const char*)A2 + m * 256 + ((c ^ (m & 15)) << 4));
      }
  }
  __syncthreads();   // A2 regs loaded; Bs region now reusable for B slices

  // ---- loop-invariant address precompute ----
  unsigned aoff[4][4];   // [kg 0..3][ii] byte offsets into A1
  #pragma unroll
  for (int kg = 0; kg < 4; kg++)
    #pragma unroll
    for (int ii = 0; ii < 4; ii++){
      const int m = wy * 64 + ii * 16 + lm;
      const int ca = kg * 4 + l4;
      aoff[kg][ii] = (unsigned)(m * 256 + ((ca ^ (m & 15)) << 4));
    }
  unsigned boff[2][2][4];  // [buf][ks2][jj] byte offsets into Bs
  #pragma unroll
  for (int buf = 0; buf < 2; buf++)
    #pragma unroll
    for (int ks2 = 0; ks2 < 2; ks2++)
      #pragma unroll
      for (int jj = 0; jj < 4; jj++){
        const int n = wx * 64 + jj * 16 + lm;
        const int c2 = ks2 * 4 + l4;
        boff[buf][ks2][jj] = (unsigned)(buf * 16384 + n * 128 + ((c2 ^ (n & 7)) << 4));
      }
  // stageB per-lane invariants
  const char* gBj[4];
  unsigned dstj[4];
  {
    const int r8 = lane >> 3, p = lane & 7;
    #pragma unroll
    for (int j = 0; j < 4; j++){
      const int row = wv * 32 + j * 8 + r8;
      const int gc = p ^ (row & 7);
      gBj[j] = (const char*)cB + (size_t)row * 512 + (gc << 4);
      dstj[j] = (unsigned)((wv * 32 + j * 8) * 128);
    }
  }

  auto stageB = [&](int S2){
    const int ss = S2 & 3, cc = S2 >> 2;
    const int buf = (S2 & 1) * 16384;
    const size_t soff = (size_t)(cc * 65536 + ss * 128);   // scalar (wave-uniform)
    #pragma unroll
    for (int j = 0; j < 4; j++)
      g2lds16(gBj[j] + soff, (char*)Bs + buf + dstj[j]);
  };

  unsigned k1[16], k2[16];
  #pragma unroll
  for (int i = 0; i < 16; i++){ k1[i] = 0xFFFFFFFFu; k2[i] = 0xFFFFFFFFu; }

  f32x4 acc[4][4];
  float bn125[4];

  stageB(0);
  __syncthreads();

  for (int c = 0; c < 32; c++){
    #pragma unroll
    for (int s = 0; s < 4; s++){
      const int S = c * 4 + s;
      if (S + 1 < 128) stageB(S + 1);
      if (s == 0){
        #pragma unroll
        for (int jj = 0; jj < 4; jj++)
          bn125[jj] = b32[h * 4096 + c * 128 + wx * 64 + jj * 16 + lm] + 0.125f;
        #pragma unroll
        for (int ii = 0; ii < 4; ii++)
          #pragma unroll
          for (int jj = 0; jj < 4; jj++)
            acc[ii][jj] = (f32x4){0.f, 0.f, 0.f, 0.f};
      }
      #pragma unroll
      for (int ks2 = 0; ks2 < 2; ks2++){
        const int kg = s * 2 + ks2;          // 0..7 (compile-time)
        bf16x8 bf[4], af[4];
        #pragma unroll
        for (int jj = 0; jj < 4; jj++)
          bf[jj] = *(const bf16x8*)((const char*)Bs + boff[s & 1][ks2][jj]);
        if (kg < 4){
          #pragma unroll
          for (int ii = 0; ii < 4; ii++)
            af[ii] = *(const bf16x8*)((const char*)A1 + aoff[kg][ii]);
        } else {
          #pragma unroll
          for (int ii = 0; ii < 4; ii++) af[ii] = a2[kg - 4][ii];
        }
        #pragma unroll
        for (int ii = 0; ii < 4; ii++)
          #pragma unroll
          for (int jj = 0; jj < 4; jj++)
            acc[ii][jj] = __builtin_amdgcn_mfma_f32_16x16x32_bf16(af[ii], bf[jj], acc[ii][jj], 0, 0, 0);
      }
      if (s == 3){
        // rank by float bits of (b - 2s + 0.125) > 0; (c<<2)|jj packed in low 7 bits
        unsigned pk[4];
        #pragma unroll
        for (int jj = 0; jj < 4; jj++) pk[jj] = (unsigned)((c << 2) | jj);
        #pragma unroll
        for (int ii = 0; ii < 4; ii++){
          #pragma unroll
          for (int r = 0; r < 4; r++){
            const int rk = ii * 4 + r;
            unsigned kb[4];
            #pragma unroll
            for (int jj = 0; jj < 4; jj++){
              const float v = fmaf(-2.f, acc[ii][jj][r], bn125[jj]);
              kb[jj] = (__float_as_uint(v) & 0xFFFFFF80u) | pk[jj];
            }
            // smallest-2-of-4
            const unsigned lo01 = umin2(kb[0], kb[1]), hi01 = umax2(kb[0], kb[1]);
            const unsigned lo23 = umin2(kb[2], kb[3]), hi23 = umax2(kb[2], kb[3]);
            const unsigned s1 = umin2(lo01, lo23);
            const unsigned s2 = umin2(umax2(lo01, lo23), umin2(hi01, hi23));
            // merge two sorted pairs (k1,k2) x (s1,s2) -> top-2
            const unsigned t = umax2(k1[rk], s1);
            k1[rk] = umin2(k1[rk], s1);
            k2[rk] = umin2(umin2(k2[rk], t), s2);
          }
        }
      }
      __syncthreads();
    }
  }

  // ---- finalize keys to (qi<<12)|col and merge: per row, top-8 of 64 keys ----
  const unsigned colbase = (unsigned)(wx * 64 + lm);
  auto fin = [colbase](unsigned key)->unsigned {
    const float v125 = __uint_as_float(key & 0xFFFFFF80u);
    int qi = (int)(v125 * 4194304.f);          // (v + 0.125) * 2^22
    qi = qi < 0 ? 0 : (qi > 0xFFFFF ? 0xFFFFF : qi);
    const unsigned cc = (key >> 2) & 31u, jj = key & 3u;
    return ((unsigned)qi << 12) | (cc * 128u + jj * 16u + colbase);
  };
  unsigned* red = (unsigned*)&A1[0];        // 32 KB = 8192 u32 = [128 rows][64]
  #pragma unroll
  for (int rk = 0; rk < 16; rk++){
    const int srow = wy * 64 + (rk >> 2) * 16 + l4 * 4 + (rk & 3);
    red[srow * 64 + wx * 32 + lm * 2 + 0] = fin(k1[rk]);
    red[srow * 64 + wx * 32 + lm * 2 + 1] = fin(k2[rk]);
  }
  __syncthreads();
  if (tid < 128){
    unsigned best[8];
    #pragma unroll
    for (int j = 0; j < 8; j++) best[j] = 0xFFFFFFFFu;
    for (int i = 0; i < 64; i++){
      unsigned k = red[tid * 64 + i];
      if (k < best[7]){
        best[7] = k;
        #pragma unroll
        for (int j = 7; j > 0; j--){
          if (best[j] < best[j-1]){ unsigned tmp = best[j]; best[j] = best[j-1]; best[j-1] = tmp; }
        }
      }
    }
    const size_t base = ((size_t)(tok0 + tid) * 2 + h) * 8;
    #pragma unroll
    for (int j = 0; j < 8; j++) cand[base + j] = h * 4096 + (int)(best[j] & 0xFFFu);
  }
}

// ========== phase 2: rescore + fused quantize/loss, LDS-tiled x/outq ==========
// (r9 variant, -16us: 64B-granule staging of x and outq; math bit-identical)
__global__ void k_pick(const float* __restrict__ x, const float* __restrict__ cb,
                       const float* __restrict__ a32, const float* __restrict__ b32,
                       const int* __restrict__ cand, int* __restrict__ idx,
                       int* __restrict__ icnt, float* __restrict__ out_idx,
                       float* __restrict__ outq, double* __restrict__ lpart)
{
  __shared__ float xt[256][17];
  __shared__ double wred[4];
  const int tid = threadIdx.x;
  const int bx = blockIdx.x;              // 2048 blocks x 16 tokens
  const int n0 = bx * 16;
  const int b = n0 >> 10, hw0 = n0 & 1023;
  const int wv = tid >> 6, lane = tid & 63;

  // ---- stage x[b, :, hw0..hw0+15] -> xt (64B-granule reads) ----
  {
    const int cr = lane >> 2, hq = (lane & 3) * 4;
    #pragma unroll
    for (int j = 0; j < 4; j++){
      const int c = wv * 64 + j * 16 + cr;
      float4 v = *(const float4*)(x + ((size_t)(b * 256 + c) << 10) + hw0 + hq);
      xt[c][hq] = v.x; xt[c][hq+1] = v.y; xt[c][hq+2] = v.z; xt[c][hq+3] = v.w;
    }
  }
  __syncthreads();

  const int tq = lane & 3, cg = lane >> 2;
  const int tl = wv * 4 + tq;             // token-local 0..15
  const int n = n0 + tl;

  float z[16];
  #pragma unroll
  for (int j = 0; j < 16; j++) z[j] = xt[cg * 16 + j][tl];

  const float an = a32[n];
  float bestd = 3.4e38f; int besti = 0x7fffffff;
  for (int j = 0; j < 16; j++){
    const int ci = cand[(size_t)n * 16 + j];     // uniform across the 16 lanes
    if (ci < 0 || ci >= KCB) continue;
    const float* ep = cb + (size_t)ci * DIM + cg * 16;
    float4 e0 = *(const float4*)(ep + 0);
    float4 e1 = *(const float4*)(ep + 4);
    float4 e2 = *(const float4*)(ep + 8);
    float4 e3 = *(const float4*)(ep + 12);
    double se = (double)z[0]*e0.x + (double)z[1]*e0.y + (double)z[2]*e0.z + (double)z[3]*e0.w
              + (double)z[4]*e1.x + (double)z[5]*e1.y + (double)z[6]*e1.z + (double)z[7]*e1.w
              + (double)z[8]*e2.x + (double)z[9]*e2.y + (double)z[10]*e2.z + (double)z[11]*e2.w
              + (double)z[12]*e3.x + (double)z[13]*e3.y + (double)z[14]*e3.z + (double)z[15]*e3.w;
    se += __shfl_xor(se, 4, 64);
    se += __shfl_xor(se, 8, 64);
    se += __shfl_xor(se, 16, 64);
    se += __shfl_xor(se, 32, 64);
    const float A = an + b32[ci];
    const float d32 = (float)((double)A - 2.0 * se);
    if (d32 < bestd || (d32 == bestd && ci < besti)){ bestd = d32; besti = ci; }
  }

  // ---- fused quantize (in place into xt) + loss ----
  double p = 0.0;
  {
    const float* ep = cb + (size_t)besti * DIM + cg * 16;
    float4 e0 = *(const float4*)(ep + 0);
    float4 e1 = *(const float4*)(ep + 4);
    float4 e2 = *(const float4*)(ep + 8);
    float4 e3 = *(const float4*)(ep + 12);
    float q[16] = { e0.x, e0.y, e0.z, e0.w, e1.x, e1.y, e1.z, e1.w,
                    e2.x, e2.y, e2.z, e2.w, e3.x, e3.y, e3.z, e3.w };
    #pragma unroll
    for (int j = 0; j < 16; j++){
      const float qd = q[j] - z[j];
      xt[cg * 16 + j][tl] = z[j] + qd;
      p += (double)(qd * qd);
    }
  }
  #pragma unroll
  for (int o = 32; o > 0; o >>= 1) p += __shfl_down(p, o, 64);
  if ((tid & 63) == 0) wred[tid >> 6] = p;

  if (cg == 0){
    idx[n] = besti;
    atomicAdd(icnt + besti, 1);
    out_idx[n] = (float)besti;
  }
  __syncthreads();

  // ---- write outq (64B-granule writes) ----
  {
    const int cr = lane >> 2, hq = (lane & 3) * 4;
    #pragma unroll
    for (int j = 0; j < 4; j++){
      const int c = wv * 64 + j * 16 + cr;
      float4 v = { xt[c][hq], xt[c][hq+1], xt[c][hq+2], xt[c][hq+3] };
      *(float4*)(outq + ((size_t)(b * 256 + c) << 10) + hw0 + hq) = v;
    }
  }
  if (tid == 0) lpart[bx] = (wred[0] + wred[1]) + (wred[2] + wred[3]);
}

// ========== bucket tokens by code (scan fused: each block scans icnt in LDS) ==========
__global__ void k_perm(const int* __restrict__ idx, const int* __restrict__ icnt,
                       int* __restrict__ cur, int* __restrict__ perm,
                       int* __restrict__ offs)
{
  __shared__ int offs_l[8192];
  __shared__ int sums[256];
  const int tid = threadIdx.x;
  int loc[32];
  int s = 0;
  #pragma unroll
  for (int i = 0; i < 32; i++){ loc[i] = s; s += icnt[tid * 32 + i]; }
  sums[tid] = s;
  #pragma unroll
  for (int off = 1; off < 256; off <<= 1){
    __syncthreads();
    const int add = (tid >= off) ? sums[tid - off] : 0;
    __syncthreads();
    sums[tid] += add;
  }
  __syncthreads();
  const int pre = (tid == 0) ? 0 : sums[tid - 1];
  #pragma unroll
  for (int i = 0; i < 32; i++) offs_l[tid * 32 + i] = pre + loc[i];
  if (blockIdx.x == 0){
    #pragma unroll
    for (int i = 0; i < 32; i++) offs[tid * 32 + i] = pre + loc[i];
  }
  __syncthreads();
  const int t = blockIdx.x * 256 + tid;        // 32,768
  const int code = idx[t];
  const int slot = atomicAdd(cur + code, 1);
  perm[offs_l[code] + slot] = t;
}

// ====== dw segment-sum + new_weight/new_codebook/new_count + e_loss (fused) ======
// Gather loop batched 4-wide to break the perm->flatB dependency chain
// (4 independent row gathers in flight). Accumulation order UNCHANGED
// (s += v0; += v1; += v2; += v3 in the original i sequence) -> bit-exact,
// empty codes still exact 0.0.
__global__ void k_dwf(const unsigned short* __restrict__ flatB,
                      const int* __restrict__ offs, const int* __restrict__ icnt,
                      const int* __restrict__ perm,
                      const float* __restrict__ ema_w, const float* __restrict__ ema_count,
                      const double* __restrict__ lpart, float* __restrict__ out)
{
  const int k = blockIdx.x;                   // 8192
  const int c = threadIdx.x;                  // 256
  const int start = offs[k], cnt = icnt[k];
  float s = 0.f;
  int i = 0;
  for (; i + 4 <= cnt; i += 4){
    const int n0 = perm[start + i + 0];
    const int n1 = perm[start + i + 1];
    const int n2 = perm[start + i + 2];
    const int n3 = perm[start + i + 3];
    const float v0 = __uint_as_float(((unsigned)flatB[((size_t)n0 << 8) + c]) << 16);
    const float v1 = __uint_as_float(((unsigned)flatB[((size_t)n1 << 8) + c]) << 16);
    const float v2 = __uint_as_float(((unsigned)flatB[((size_t)n2 << 8) + c]) << 16);
    const float v3 = __uint_as_float(((unsigned)flatB[((size_t)n3 << 8) + c]) << 16);
    s += v0; s += v1; s += v2; s += v3;
  }
  for (; i < cnt; i++){
    const int n = perm[start + i];
    s += __uint_as_float(((unsigned)flatB[((size_t)n << 8) + c]) << 16);
  }
  // new_count (same exprs as before)
  float ct1 = ema_count[k] * 0.95f;
  float ct2 = 0.05f * (float)cnt;
  float sc  = ct1 + ct2;
  float sc2 = sc + 1e-5f;
  const float DEN = (float)(32768.0 + 8192.0 * 1e-5);
  float nc = (sc2 / DEN) * 32768.0f;
  if (c == 0) out[O_CNT + k] = nc;
  {
    #pragma clang fp contract(off)
    const int t = k * 256 + c;
    float w = ema_w[t];
    float t1 = w * 0.95f;
    float t2 = 0.05f * s;
    float nw = t1 + t2;        // np op order; bit-exact for empty codes (s==0)
    out[O_W + t]  = nw;
    out[O_CB + t] = nw / nc;
  }
  if (k == 0){
    __shared__ double sred[256];
    double ls = 0.0;
    for (int i2 = c; i2 < 2048; i2 += 256) ls += lpart[i2];
    sred[c] = ls;
    __syncthreads();
    for (int off = 128; off > 0; off >>= 1){
      if (c < off) sred[c] += sred[c + off];
      __syncthreads();
    }
    if (c == 0) out[O_LOSS] = 0.25f * (float)(sred[0] / 8388608.0);
  }
}

// ===================== launch =====================
extern "C" void kernel_launch(void* const* d_in, const int* in_sizes, int n_in,
                              void* d_out, int out_size, void* d_ws, size_t ws_size,
                              hipStream_t stream)
{
  const float* x         = (const float*)d_in[0];
  const float* cb        = (const float*)d_in[1];
  const float* ema_count = (const float*)d_in[2];
  const float* ema_w     = (const float*)d_in[3];
  float* out = (float*)d_out;
  float* ws  = (float*)d_ws;

  unsigned short* flatB = (unsigned short*)(ws + WS_FLATB);
  unsigned short* cbB   = (unsigned short*)(ws + WS_CBB);
  float*  a32    = ws + WS_A32;
  float*  b32    = ws + WS_B32;
  int*    idxp   = (int*)(ws + WS_IDX);
  int*    candp  = (int*)(ws + WS_CAND);
  int*    icnt   = (int*)(ws + WS_ICNT);
  int*    curp   = (int*)(ws + WS_CUR);
  int*    offs   = (int*)(ws + WS_OFFS);
  int*    permp  = (int*)(ws + WS_PERM);
  double* lpart  = (double*)(ws + WS_LPART);

  k_prep <<<4128, 256, 0, stream>>>(x, cb, flatB, cbB, a32, b32, icnt, curp);
  k_dist <<<512,  256, 0, stream>>>(flatB, cbB, b32, candp);
  k_pick <<<2048, 256, 0, stream>>>(x, cb, a32, b32, candp, idxp, icnt,
                                    out + O_IDX, out + O_Q, lpart);
  k_perm <<<128,  256, 0, stream>>>(idxp, icnt, curp, permp, offs);
  k_dwf  <<<8192, 256, 0, stream>>>(flatB, offs, icnt, permp, ema_w, ema_count,
                                    lpart, out);
}